// Round 5
// baseline (967.052 us; speedup 1.0000x reference)
//
// ===========================================================================
// FlowerAttention fused pipeline (MI355X / gfx950).
//
// v4 = v3 + __launch_bounds__(256,4) on flash_attn ONLY.
// History:
//  v1 (baseline): 355us flash_attn, VGPR 124, occ 22%, conflicts 2.7e7.
//  v2 (swizzle+pipeline+lean-sm): conflicts->0 (proven) but VGPR 152 ->
//      occupancy cliff (11.8%), 486us.
//  v3 (swizzle+lean-sm, v1 sync structure): VGPR 148 (still >128 cliff),
//      occ 11.5%, 452us. MFMA work identical across versions (dur*MfmaUtil
//      constant) => kernel is occupancy/latency-bound, first-order.
//  v4: force the allocator under the 128-VGPR cliff (4 waves/EU budget =
//      512/4 = 128). v1 fit ~this shape in 124, so spill risk is low.
// Predicted: VGPR<=128, occ ~22%, conflicts 0, dur ~280-300us.
// ===========================================================================
#include <hip/hip_runtime.h>
#include <hip/hip_bf16.h>

#define BSZ 4
#define SEQ 2048
#define DIM 2048
#define NH 16
#define HD 128
#define QK_LD 4096  // row stride of packed Q|K workspace
#define SCALE 0.08838834764831845f
// SCALE * log2(e): softmax done in log2 domain (exp2 is the native HW op)
#define SC2 0.12751742910198f

typedef __attribute__((ext_vector_type(8))) short bf16x8;
typedef __attribute__((ext_vector_type(4))) float f32x4;

// Async global->LDS, 16B per lane. LDS dest = wave-uniform base + lane*16.
#define GLDS16(g, l)                                                           \
  __builtin_amdgcn_global_load_lds(                                           \
      (const __attribute__((address_space(1))) void*)(g),                     \
      (__attribute__((address_space(3))) void*)(l), 16, 0, 0)

__device__ inline short f2b(float f) {
  __hip_bfloat16 h = __float2bfloat16(f);
  short s;
  __builtin_memcpy(&s, &h, 2);
  return s;
}

// Load 16 contiguous fp32, convert to bf16, store 32B to LDS (two b128).
__device__ inline void stage16(const float* gp, __hip_bfloat16* lp) {
  float4 q0 = ((const float4*)gp)[0], q1 = ((const float4*)gp)[1];
  float4 q2 = ((const float4*)gp)[2], q3 = ((const float4*)gp)[3];
  bf16x8 v0, v1;
  v0[0] = f2b(q0.x); v0[1] = f2b(q0.y); v0[2] = f2b(q0.z); v0[3] = f2b(q0.w);
  v0[4] = f2b(q1.x); v0[5] = f2b(q1.y); v0[6] = f2b(q1.z); v0[7] = f2b(q1.w);
  v1[0] = f2b(q2.x); v1[1] = f2b(q2.y); v1[2] = f2b(q2.z); v1[3] = f2b(q2.w);
  v1[4] = f2b(q3.x); v1[5] = f2b(q3.y); v1[6] = f2b(q3.z); v1[7] = f2b(q3.w);
  *(bf16x8*)lp = v0;
  *(bf16x8*)(lp + 8) = v1;
}

// Per-batch output slice base, dtype-aware (fl=1: bf16, fl=0: fp32).
__device__ inline char* out_slice(void* outv, int b, int fl) {
  return (char*)outv + (size_t)b * (size_t)SEQ * DIM * (fl ? 2u : 4u);
}

// ---------------------------------------------------------------------------
// Detect input dtype from w_qkv bit patterns; canonicalize qw/kw to bf16.
// ---------------------------------------------------------------------------
__global__ __launch_bounds__(256)
void detect_canon(const unsigned int* __restrict__ wbits,
                  const void* __restrict__ qw, const void* __restrict__ kw,
                  __hip_bfloat16* __restrict__ qwb,
                  __hip_bfloat16* __restrict__ kwb, int* __restrict__ flag) {
  __shared__ int cnt;
  const int t = threadIdx.x;
  if (t == 0) cnt = 0;
  __syncthreads();
  int local = 0;
  for (int i = 0; i < 4; ++i) {
    unsigned int e = (wbits[t * 4 + i] >> 7) & 0xFF;
    if (e >= 96 && e < 160) local++;
  }
  atomicAdd(&cnt, local);
  __syncthreads();
  const int f = (cnt >= 768) ? 1 : 0;  // 1 = bf16 tensors, 0 = fp32 tensors
  if (t == 0) *flag = f;
  if (t < 128)
    qwb[t] = f ? ((const __hip_bfloat16*)qw)[t]
               : __float2bfloat16(((const float*)qw)[t]);
  else
    kwb[t - 128] = f ? ((const __hip_bfloat16*)kw)[t - 128]
                     : __float2bfloat16(((const float*)kw)[t - 128]);
}

// ---------------------------------------------------------------------------
// Elementwise canonicalize a tensor to bf16 (8 elts/thread). fl=1: raw copy.
// ---------------------------------------------------------------------------
__global__ __launch_bounds__(256)
void convert_bf16(const void* __restrict__ in, __hip_bfloat16* __restrict__ out,
                  const int* __restrict__ flag) {
  const int fl = *flag;
  long i = ((long)blockIdx.x * 256 + threadIdx.x) * 8;
  if (fl) {
    *(float4*)(out + i) = *(const float4*)((const __hip_bfloat16*)in + i);
  } else {
    const float* p = (const float*)in + i;
    float4 a = ((const float4*)p)[0], b = ((const float4*)p)[1];
    bf16x8 o;
    o[0] = f2b(a.x); o[1] = f2b(a.y); o[2] = f2b(a.z); o[3] = f2b(a.w);
    o[4] = f2b(b.x); o[5] = f2b(b.y); o[6] = f2b(b.z); o[7] = f2b(b.w);
    *(bf16x8*)(out + i) = o;
  }
}

// ===========================================================================
// TIER A GEMMs (m97 structure, both operands via global_load_lds).
// ===========================================================================

__global__ __launch_bounds__(256)
void gemm_qkv_full(const __hip_bfloat16* __restrict__ A,
                   const __hip_bfloat16* __restrict__ B,
                   __hip_bfloat16* __restrict__ qk, void* __restrict__ outv,
                   const int* __restrict__ flag) {
  __shared__ __hip_bfloat16 As[128 * 32];
  __shared__ __hip_bfloat16 Bs[128 * 32];
  const int t = threadIdx.x, wave = t >> 6, lane = t & 63;
  const int quad = lane >> 4, l16 = lane & 15;
  const int wm = (wave & 1) * 64, wn = (wave >> 1) * 64;
  const long bm = (long)blockIdx.x * 128, bn = (long)blockIdx.y * 128;
  const int fl = *flag;

  f32x4 acc[4][4] = {};
  for (int k0 = 0; k0 < DIM; k0 += 32) {
    __syncthreads();
    for (int i = 0; i < 2; ++i) {
      int c = wave * 64 + lane + i * 256;
      int row = c >> 2, kc = c & 3;
      GLDS16(A + (bm + row) * DIM + k0 + kc * 8, As + (wave * 64 + i * 256) * 8);
      GLDS16(B + (bn + row) * DIM + k0 + kc * 8, Bs + (wave * 64 + i * 256) * 8);
    }
    __syncthreads();
    bf16x8 aF[4], bF[4];
    for (int mt = 0; mt < 4; ++mt)
      aF[mt] = *(const bf16x8*)(As + (wm + mt * 16 + l16) * 32 + quad * 8);
    for (int nt = 0; nt < 4; ++nt)
      bF[nt] = *(const bf16x8*)(Bs + (wn + nt * 16 + l16) * 32 + quad * 8);
    for (int mt = 0; mt < 4; ++mt)
      for (int nt = 0; nt < 4; ++nt)
        acc[mt][nt] = __builtin_amdgcn_mfma_f32_16x16x32_bf16(
            aF[mt], bF[nt], acc[mt][nt], 0, 0, 0);
  }

  if (bn < 4096) {  // Q|K block
    for (int mt = 0; mt < 4; ++mt) {
      long gr = bm + wm + mt * 16 + quad * 4;
      for (int nt = 0; nt < 4; ++nt) {
        long gc = bn + wn + nt * 16 + l16;
        for (int r = 0; r < 4; ++r)
          qk[(gr + r) * QK_LD + gc] = __float2bfloat16(acc[mt][nt][r]);
      }
    }
  } else {  // V block: transposed bf16 store into the owning batch's slice
    for (int mt = 0; mt < 4; ++mt) {
      long gr = bm + wm + mt * 16 + quad * 4;
      __hip_bfloat16* vtb = (__hip_bfloat16*)out_slice(outv, (int)(gr >> 11), fl);
      long s = gr & 2047;
      for (int nt = 0; nt < 4; ++nt) {
        long col = bn - 4096 + wn + nt * 16 + l16;  // h*128 + d
        for (int r = 0; r < 4; ++r)
          vtb[col * SEQ + s + r] = __float2bfloat16(acc[mt][nt][r]);
      }
    }
  }
}

__global__ __launch_bounds__(256)
void gemm_proj_full(const __hip_bfloat16* __restrict__ A,
                    const __hip_bfloat16* __restrict__ B,
                    void* __restrict__ outv, const int* __restrict__ flag) {
  __shared__ __hip_bfloat16 As[128 * 32];
  __shared__ __hip_bfloat16 Bs[128 * 32];
  const int t = threadIdx.x, wave = t >> 6, lane = t & 63;
  const int quad = lane >> 4, l16 = lane & 15;
  const int wm = (wave & 1) * 64, wn = (wave >> 1) * 64;
  const long bm = (long)blockIdx.x * 128, bn = (long)blockIdx.y * 128;
  const int fl = *flag;

  f32x4 acc[4][4] = {};
  for (int k0 = 0; k0 < DIM; k0 += 32) {
    __syncthreads();
    for (int i = 0; i < 2; ++i) {
      int c = wave * 64 + lane + i * 256;
      int row = c >> 2, kc = c & 3;
      GLDS16(A + (bm + row) * QK_LD + k0 + kc * 8, As + (wave * 64 + i * 256) * 8);
      GLDS16(B + (bn + row) * DIM + k0 + kc * 8, Bs + (wave * 64 + i * 256) * 8);
    }
    __syncthreads();
    bf16x8 aF[4], bF[4];
    for (int mt = 0; mt < 4; ++mt)
      aF[mt] = *(const bf16x8*)(As + (wm + mt * 16 + l16) * 32 + quad * 8);
    for (int nt = 0; nt < 4; ++nt)
      bF[nt] = *(const bf16x8*)(Bs + (wn + nt * 16 + l16) * 32 + quad * 8);
    for (int mt = 0; mt < 4; ++mt)
      for (int nt = 0; nt < 4; ++nt)
        acc[mt][nt] = __builtin_amdgcn_mfma_f32_16x16x32_bf16(
            aF[mt], bF[nt], acc[mt][nt], 0, 0, 0);
  }

  for (int mt = 0; mt < 4; ++mt) {
    long gr = bm + wm + mt * 16 + quad * 4;
    for (int nt = 0; nt < 4; ++nt) {
      long gc = bn + wn + nt * 16 + l16;
      for (int r = 0; r < 4; ++r) {
        long idx = (gr + r) * DIM + gc;
        if (fl) ((__hip_bfloat16*)outv)[idx] = __float2bfloat16(acc[mt][nt][r]);
        else    ((float*)outv)[idx] = acc[mt][nt][r];
      }
    }
  }
}

// ===========================================================================
// TIER B GEMMs (per-batch, dual staging — fallback, known-good).
// ===========================================================================

__global__ __launch_bounds__(256)
void gemm_qkv(const void* __restrict__ xin, const void* __restrict__ win,
              __hip_bfloat16* __restrict__ qk, void* __restrict__ outv,
              const int* __restrict__ flag, int b) {
  __shared__ __hip_bfloat16 As[128 * 32];
  __shared__ __hip_bfloat16 Bs[128 * 32];
  const int t = threadIdx.x, wave = t >> 6, lane = t & 63;
  const int quad = lane >> 4, l16 = lane & 15;
  const int wm = (wave & 1) * 64, wn = (wave >> 1) * 64;
  const long bm = (long)blockIdx.x * 128, bn = (long)blockIdx.y * 128;
  const int fl = *flag;
  const __hip_bfloat16* Ab = (const __hip_bfloat16*)xin + (long)b * SEQ * DIM;
  const __hip_bfloat16* Bb = (const __hip_bfloat16*)win;
  const float* Af = (const float*)xin + (long)b * SEQ * DIM;
  const float* Bf = (const float*)win;

  f32x4 acc[4][4] = {};
  for (int k0 = 0; k0 < DIM; k0 += 32) {
    __syncthreads();
    if (fl) {
      for (int i = 0; i < 2; ++i) {
        int c = wave * 64 + lane + i * 256;
        int row = c >> 2, kc = c & 3;
        GLDS16(Ab + (bm + row) * DIM + k0 + kc * 8, As + (wave * 64 + i * 256) * 8);
        GLDS16(Bb + (bn + row) * DIM + k0 + kc * 8, Bs + (wave * 64 + i * 256) * 8);
      }
    } else {
      int row = t >> 1, cb = k0 + (t & 1) * 16;
      stage16(Af + (bm + row) * DIM + cb, As + t * 16);
      stage16(Bf + (bn + row) * DIM + cb, Bs + t * 16);
    }
    __syncthreads();
    bf16x8 aF[4], bF[4];
    for (int mt = 0; mt < 4; ++mt)
      aF[mt] = *(const bf16x8*)(As + (wm + mt * 16 + l16) * 32 + quad * 8);
    for (int nt = 0; nt < 4; ++nt)
      bF[nt] = *(const bf16x8*)(Bs + (wn + nt * 16 + l16) * 32 + quad * 8);
    for (int mt = 0; mt < 4; ++mt)
      for (int nt = 0; nt < 4; ++nt)
        acc[mt][nt] = __builtin_amdgcn_mfma_f32_16x16x32_bf16(
            aF[mt], bF[nt], acc[mt][nt], 0, 0, 0);
  }

  if (bn < 4096) {
    for (int mt = 0; mt < 4; ++mt) {
      long gr = bm + wm + mt * 16 + quad * 4;
      for (int nt = 0; nt < 4; ++nt) {
        long gc = bn + wn + nt * 16 + l16;
        for (int r = 0; r < 4; ++r)
          qk[(gr + r) * QK_LD + gc] = __float2bfloat16(acc[mt][nt][r]);
      }
    }
  } else {
    __hip_bfloat16* vtb = (__hip_bfloat16*)out_slice(outv, b, fl);
    for (int mt = 0; mt < 4; ++mt) {
      long gr = bm + wm + mt * 16 + quad * 4;
      for (int nt = 0; nt < 4; ++nt) {
        long col = bn - 4096 + wn + nt * 16 + l16;
        for (int r = 0; r < 4; ++r)
          vtb[col * SEQ + gr + r] = __float2bfloat16(acc[mt][nt][r]);
      }
    }
  }
}

__global__ __launch_bounds__(256)
void gemm_proj(const __hip_bfloat16* __restrict__ A, const void* __restrict__ win,
               void* __restrict__ outv, const int* __restrict__ flag, int b) {
  __shared__ __hip_bfloat16 As[128 * 32];
  __shared__ __hip_bfloat16 Bs[128 * 32];
  const int t = threadIdx.x, wave = t >> 6, lane = t & 63;
  const int quad = lane >> 4, l16 = lane & 15;
  const int wm = (wave & 1) * 64, wn = (wave >> 1) * 64;
  const long bm = (long)blockIdx.x * 128, bn = (long)blockIdx.y * 128;
  const int fl = *flag;
  const __hip_bfloat16* Bb = (const __hip_bfloat16*)win;
  const float* Bf = (const float*)win;

  f32x4 acc[4][4] = {};
  for (int k0 = 0; k0 < DIM; k0 += 32) {
    __syncthreads();
    for (int i = 0; i < 2; ++i) {
      int c = wave * 64 + lane + i * 256;
      int row = c >> 2, kc = c & 3;
      GLDS16(A + (bm + row) * QK_LD + k0 + kc * 8, As + (wave * 64 + i * 256) * 8);
    }
    if (fl) {
      for (int i = 0; i < 2; ++i) {
        int c = wave * 64 + lane + i * 256;
        int row = c >> 2, kc = c & 3;
        GLDS16(Bb + (bn + row) * DIM + k0 + kc * 8, Bs + (wave * 64 + i * 256) * 8);
      }
    } else {
      int row = t >> 1, cb = k0 + (t & 1) * 16;
      stage16(Bf + (bn + row) * DIM + cb, Bs + t * 16);
    }
    __syncthreads();
    bf16x8 aF[4], bF[4];
    for (int mt = 0; mt < 4; ++mt)
      aF[mt] = *(const bf16x8*)(As + (wm + mt * 16 + l16) * 32 + quad * 8);
    for (int nt = 0; nt < 4; ++nt)
      bF[nt] = *(const bf16x8*)(Bs + (wn + nt * 16 + l16) * 32 + quad * 8);
    for (int mt = 0; mt < 4; ++mt)
      for (int nt = 0; nt < 4; ++nt)
        acc[mt][nt] = __builtin_amdgcn_mfma_f32_16x16x32_bf16(
            aF[mt], bF[nt], acc[mt][nt], 0, 0, 0);
  }

  char* Cb = out_slice(outv, b, fl);
  for (int mt = 0; mt < 4; ++mt) {
    long gr = bm + wm + mt * 16 + quad * 4;
    for (int nt = 0; nt < 4; ++nt) {
      long gc = bn + wn + nt * 16 + l16;
      for (int r = 0; r < 4; ++r) {
        long idx = (gr + r) * DIM + gc;
        if (fl) ((__hip_bfloat16*)Cb)[idx] = __float2bfloat16(acc[mt][nt][r]);
        else    ((float*)Cb)[idx] = acc[mt][nt][r];
      }
    }
  }
}

// ===========================================================================
// Shared kernels.
// ===========================================================================

// Per-row RMSNorm + RoPE, vectorized: lane loads uint (2 bf16), shfl
// redistributes to the (d, d+64) RoPE pairing, inverse shfl scatters back.
__global__ __launch_bounds__(256)
void norm_rope(__hip_bfloat16* __restrict__ qk,
               const __hip_bfloat16* __restrict__ qwb,
               const __hip_bfloat16* __restrict__ kwb) {
  const int wave = threadIdx.x >> 6, lane = threadIdx.x & 63;
  const int gid = blockIdx.x * 4 + wave;
  const int h = gid & 15, tt = (gid >> 4) & 1, row = gid >> 5;
  const int s = row & 2047;

  __hip_bfloat16* p = qk + (long)row * QK_LD + tt * DIM + h * HD;
  unsigned int u = ((const unsigned int*)p)[lane];  // elems (2l, 2l+1)

  // gather pair (d=lane, d=lane+64)
  unsigned int x = (unsigned int)__shfl((int)u, lane >> 1);
  unsigned int y = (unsigned int)__shfl((int)u, 32 + (lane >> 1));
  float v1 = __uint_as_float((lane & 1) ? (x & 0xFFFF0000u) : (x << 16));
  float v2 = __uint_as_float((lane & 1) ? (y & 0xFFFF0000u) : (y << 16));

  float ss = v1 * v1 + v2 * v2;
  for (int off = 1; off < 64; off <<= 1) ss += __shfl_xor(ss, off);
  float inv = rsqrtf(ss * (1.0f / 128.0f) + 1e-6f);

  const __hip_bfloat16* w = tt ? kwb : qwb;
  float n1 = v1 * inv * __bfloat162float(w[lane]);
  float n2 = v2 * inv * __bfloat162float(w[lane + 64]);

  float freq = exp2f(-5.0f * (float)lane * (1.0f / 64.0f));
  float ang = (float)s * freq;
  float c = cosf(ang), sn = sinf(ang);
  float r1 = n1 * c - n2 * sn;  // elem d = lane
  float r2 = n2 * c + n1 * sn;  // elem d = lane + 64

  // scatter back: lane stores elems (2l, 2l+1)
  float z1lo = __shfl(r1, (2 * lane) & 63), z2lo = __shfl(r2, (2 * lane) & 63);
  float z1hi = __shfl(r1, (2 * lane + 1) & 63), z2hi = __shfl(r2, (2 * lane + 1) & 63);
  float lo = (lane < 32) ? z1lo : z2lo;
  float hi = (lane < 32) ? z1hi : z2hi;
  unsigned int ou = (unsigned int)(unsigned short)f2b(lo) |
                    ((unsigned int)(unsigned short)f2b(hi) << 16);
  ((unsigned int*)p)[lane] = ou;
}

// ---------------------------------------------------------------------------
// Flash attention, non-causal. Block = 128-query tile for one (b,h);
// 4 waves x 32 query rows. Q held in registers. K-tiles of 64.
// v4: v3 + __launch_bounds__(256,4) to force VGPR <= 128 (occupancy cliff).
// LDS 48 KB.
// ---------------------------------------------------------------------------
__global__ __launch_bounds__(256, 4)
void flash_attn(__hip_bfloat16* __restrict__ qkbase, void* __restrict__ outv,
                const int* __restrict__ flag, int b0) {
  __shared__ __hip_bfloat16 Ks[4 * 64 * 32];     // [ks=4][krow=64][32]
  __shared__ __hip_bfloat16 Vs[2 * 128 * 32];    // [ks2=2][dim=128][32 keys]
  __shared__ __hip_bfloat16 Ps[4][2 * 32 * 32];  // per-wave [ks2=2][row=32][32]

  const int t = threadIdx.x, wave = t >> 6, lane = t & 63;
  const int quad = lane >> 4, l16 = lane & 15;
  // swizzled 8-elem slot for all fragment reads (row bits 1:2 come from l16)
  const int swz = (quad ^ ((l16 >> 1) & 3)) * 8;
  const int q0 = blockIdx.x * 128, h = blockIdx.y;
  const int b = b0 + blockIdx.z;
  const int fl = *flag;
  __hip_bfloat16* qk = qkbase + (long)blockIdx.z * SEQ * QK_LD;
  __hip_bfloat16* Qg = qk + h * HD;
  const __hip_bfloat16* Kg = Qg + DIM;
  const __hip_bfloat16* Vt =
      (const __hip_bfloat16*)out_slice(outv, b, fl) + (long)h * HD * SEQ;

  // Q fragments in registers: aQ[mt][ks], rows wave*32 + mt*16 + l16
  bf16x8 aQ[2][4];
#pragma unroll
  for (int mt = 0; mt < 2; ++mt)
#pragma unroll
    for (int ks = 0; ks < 4; ++ks)
      aQ[mt][ks] = *(const bf16x8*)(Qg +
          (long)(q0 + wave * 32 + mt * 16 + l16) * QK_LD + ks * 32 + quad * 8);

  f32x4 oacc[2][8] = {};
  float m_run[2][4], l_run[2][4];  // l_run: per-lane PARTIAL sums (4 keys/lane)
#pragma unroll
  for (int mt = 0; mt < 2; ++mt)
    for (int r = 0; r < 4; ++r) { m_run[mt][r] = -1e30f; l_run[mt][r] = 0.0f; }

  for (int j0 = 0; j0 < SEQ; j0 += 64) {
    __syncthreads();  // all waves done reading Ks/Vs of previous tile
    // stage K-tile: linear LDS dest, swizzled GLOBAL source (rule 21)
    for (int i = 0; i < 4; ++i) {
      int f = wave * 64 + lane + i * 256;          // [0,1024)
      int kk = f & 3, row = (f >> 2) & 63, ks = f >> 8;
      GLDS16(Kg + (long)(j0 + row) * QK_LD + ks * 32 + (kk ^ ((row >> 1) & 3)) * 8,
             Ks + (wave * 64 + i * 256) * 8);
    }
    // stage V-tile (transposed layout in qkv output), swizzled source
    for (int i = 0; i < 4; ++i) {
      int f = wave * 64 + lane + i * 256;
      int kk = f & 3, dimr = (f >> 2) & 127, ks2 = f >> 9;
      GLDS16(Vt + (long)dimr * SEQ + j0 + ks2 * 32 + (kk ^ ((dimr >> 1) & 3)) * 8,
             Vs + (wave * 64 + i * 256) * 8);
    }
    __syncthreads();  // drains vmcnt (GLDS) + barrier

    // S = Q K^T: 32 rows x 64 keys per wave (swizzled reads, conflict-free)
    f32x4 sacc[2][4] = {};
#pragma unroll
    for (int ks = 0; ks < 4; ++ks)
#pragma unroll
      for (int nt = 0; nt < 4; ++nt) {
        bf16x8 bK = *(const bf16x8*)(Ks + (ks * 64 + nt * 16 + l16) * 32 + swz);
#pragma unroll
        for (int mt = 0; mt < 2; ++mt)
          sacc[mt][nt] = __builtin_amdgcn_mfma_f32_16x16x32_bf16(
              aQ[mt][ks], bK, sacc[mt][nt], 0, 0, 0);
      }

    // online softmax in log2 domain; max reduced across the 16-lane quad
    __hip_bfloat16* pw = &Ps[wave][0];
#pragma unroll
    for (int mt = 0; mt < 2; ++mt) {
#pragma unroll
      for (int r = 0; r < 4; ++r) {
        float p0 = sacc[mt][0][r] * SC2, p1 = sacc[mt][1][r] * SC2;
        float p2 = sacc[mt][2][r] * SC2, p3 = sacc[mt][3][r] * SC2;
        float mx = fmaxf(fmaxf(p0, p1), fmaxf(p2, p3));
        for (int off = 1; off < 16; off <<= 1)
          mx = fmaxf(mx, __shfl_xor(mx, off));
        // defer-max (T13): only rescale when some row grew past THR=8
        if (__any(mx > m_run[mt][r] + 8.0f)) {
          float mnew = fmaxf(m_run[mt][r], mx);
          float alpha = exp2f(m_run[mt][r] - mnew);
          m_run[mt][r] = mnew;
          l_run[mt][r] *= alpha;
#pragma unroll
          for (int n = 0; n < 8; ++n) oacc[mt][n][r] *= alpha;
        }
        float m = m_run[mt][r];
        float e0 = exp2f(p0 - m), e1 = exp2f(p1 - m);
        float e2 = exp2f(p2 - m), e3 = exp2f(p3 - m);
        l_run[mt][r] += (e0 + e1) + (e2 + e3);  // per-lane partial
        // P store: C-layout -> A-layout, swizzled, wave-private
        int rbase = (mt * 16 + quad * 4 + r) * 32;
        int sc = (((quad * 4 + r) >> 1) & 3) << 3;
        pw[rbase + (l16 ^ sc)] = __float2bfloat16(e0);
        pw[rbase + ((l16 + 16) ^ sc)] = __float2bfloat16(e1);
        pw[1024 + rbase + (l16 ^ sc)] = __float2bfloat16(e2);
        pw[1024 + rbase + ((l16 + 16) ^ sc)] = __float2bfloat16(e3);
      }
    }

    // O += P @ V  (intra-wave LDS RAW ordered by lgkmcnt, not __syncthreads)
#pragma unroll
    for (int ks2 = 0; ks2 < 2; ++ks2) {
      bf16x8 aP[2];
#pragma unroll
      for (int mt = 0; mt < 2; ++mt)
        aP[mt] = *(const bf16x8*)(pw + ks2 * 1024 + (mt * 16 + l16) * 32 + swz);
#pragma unroll
      for (int n = 0; n < 8; ++n) {
        bf16x8 bV = *(const bf16x8*)(Vs + (ks2 * 128 + n * 16 + l16) * 32 + swz);
#pragma unroll
        for (int mt = 0; mt < 2; ++mt)
          oacc[mt][n] = __builtin_amdgcn_mfma_f32_16x16x32_bf16(
              aP[mt], bV, oacc[mt][n], 0, 0, 0);
      }
    }
  }

  // epilogue: finish deferred l reduction, write O into the Q-slot region
#pragma unroll
  for (int mt = 0; mt < 2; ++mt)
#pragma unroll
    for (int r = 0; r < 4; ++r) {
      float l = l_run[mt][r];
      for (int off = 1; off < 16; off <<= 1) l += __shfl_xor(l, off);
      float rl = 1.0f / l;
      long s = q0 + wave * 32 + mt * 16 + quad * 4 + r;
      for (int n = 0; n < 8; ++n)
        qk[s * QK_LD + h * HD + n * 16 + l16] =
            __float2bfloat16(oacc[mt][n][r] * rl);
    }
}

// ---------------------------------------------------------------------------
extern "C" void kernel_launch(void* const* d_in, const int* in_sizes, int n_in,
                              void* d_out, int out_size, void* d_ws, size_t ws_size,
                              hipStream_t stream) {
  int* flag = (int*)d_ws;
  __hip_bfloat16* qwb = (__hip_bfloat16*)((char*)d_ws + 64);
  __hip_bfloat16* kwb = qwb + 128;
  char* base = (char*)d_ws + 1024;

  detect_canon<<<1, 256, 0, stream>>>((const unsigned int*)d_in[1], d_in[3],
                                      d_in[4], qwb, kwb, flag);

  const size_t MB = 1024ull * 1024ull;
  const size_t NEED_A = 1024 + 128 * MB;

  if (ws_size >= NEED_A) {
    // ---- Tier A: full-batch bf16 path ----
    __hip_bfloat16* xb     = (__hip_bfloat16*)base;              // 32 MiB
    __hip_bfloat16* wqkvb  = (__hip_bfloat16*)(base + 32 * MB);  // 24 MiB
    __hip_bfloat16* wprojb = (__hip_bfloat16*)(base + 56 * MB);  //  8 MiB
    __hip_bfloat16* qk     = (__hip_bfloat16*)(base + 64 * MB);  // 64 MiB

    convert_bf16<<<(BSZ * SEQ * DIM) / 2048, 256, 0, stream>>>(d_in[0], xb, flag);
    convert_bf16<<<(3 * DIM * DIM) / 2048, 256, 0, stream>>>(d_in[1], wqkvb, flag);
    convert_bf16<<<(DIM * DIM) / 2048, 256, 0, stream>>>(d_in[2], wprojb, flag);

    gemm_qkv_full<<<dim3((BSZ * SEQ) / 128, (3 * DIM) / 128), 256, 0, stream>>>(
        xb, wqkvb, qk, d_out, flag);
    norm_rope<<<(BSZ * SEQ * 2 * NH) / 4, 256, 0, stream>>>(qk, qwb, kwb);
    flash_attn<<<dim3(SEQ / 128, NH, BSZ), 256, 0, stream>>>(qk, d_out, flag, 0);
    gemm_proj_full<<<dim3((BSZ * SEQ) / 128, DIM / 128), 256, 0, stream>>>(
        qk, wprojb, d_out, flag);
  } else {
    // ---- Tier B: per-batch fallback ----
    __hip_bfloat16* qk = (__hip_bfloat16*)base;  // 16 MiB, reused per batch
    for (int b = 0; b < BSZ; ++b) {
      gemm_qkv<<<dim3(SEQ / 128, (3 * DIM) / 128), 256, 0, stream>>>(
          d_in[0], d_in[1], qk, d_out, flag, b);
      norm_rope<<<(SEQ * 2 * NH) / 4, 256, 0, stream>>>(qk, qwb, kwb);
      flash_attn<<<dim3(SEQ / 128, NH, 1), 256, 0, stream>>>(qk, d_out, flag, b);
      gemm_proj<<<dim3(SEQ / 128, DIM / 128), 256, 0, stream>>>(
          qk, d_in[2], d_out, flag, b);
    }
  }
}

// Round 6
// 868.594 us; speedup vs baseline: 1.1134x; 1.1134x over previous
//
// ===========================================================================
// FlowerAttention fused pipeline (MI355X / gfx950).
//
// v5: flash_attn restructured 4 waves x 32 rows -> 8 waves x 16 rows
// (512-thread block). Rationale: v1-v4 proved dur*MfmaUtil == const
// (occupancy/latency-bound), and the 32-rows/wave tiling has a ~144-VGPR
// architectural floor (oacc 64 + aQ 32 + sacc 32 + m/l 16) that pins the
// kernel in the 129-256 VGPR band (2 waves/SIMD). launch_bounds(256,4)
// could not fix it (v4: VGPR 148 unchanged). Halving per-wave rows halves
// the state floor to ~72 (+temps ~100) -> <=128 band, 4 waves/SIMD,
// 2x resident waves. LDS stays 48KB (Ks 16K + Vs 16K + Ps 16K),
// swizzle (conflicts 2.7e7->0, proven v2/v3) and lean softmax retained.
//
// Predicted: VGPR ~100-115, occ 11.5->~25%, conflicts 0, MfmaUtil ~24,
// flash dur 450 -> ~210-250us, total -> ~740us.
// ===========================================================================
#include <hip/hip_runtime.h>
#include <hip/hip_bf16.h>

#define BSZ 4
#define SEQ 2048
#define DIM 2048
#define NH 16
#define HD 128
#define QK_LD 4096  // row stride of packed Q|K workspace
#define SCALE 0.08838834764831845f
// SCALE * log2(e): softmax done in log2 domain (exp2 is the native HW op)
#define SC2 0.12751742910198f

typedef __attribute__((ext_vector_type(8))) short bf16x8;
typedef __attribute__((ext_vector_type(4))) float f32x4;

// Async global->LDS, 16B per lane. LDS dest = wave-uniform base + lane*16.
#define GLDS16(g, l)                                                           \
  __builtin_amdgcn_global_load_lds(                                           \
      (const __attribute__((address_space(1))) void*)(g),                     \
      (__attribute__((address_space(3))) void*)(l), 16, 0, 0)

__device__ inline short f2b(float f) {
  __hip_bfloat16 h = __float2bfloat16(f);
  short s;
  __builtin_memcpy(&s, &h, 2);
  return s;
}

// Load 16 contiguous fp32, convert to bf16, store 32B to LDS (two b128).
__device__ inline void stage16(const float* gp, __hip_bfloat16* lp) {
  float4 q0 = ((const float4*)gp)[0], q1 = ((const float4*)gp)[1];
  float4 q2 = ((const float4*)gp)[2], q3 = ((const float4*)gp)[3];
  bf16x8 v0, v1;
  v0[0] = f2b(q0.x); v0[1] = f2b(q0.y); v0[2] = f2b(q0.z); v0[3] = f2b(q0.w);
  v0[4] = f2b(q1.x); v0[5] = f2b(q1.y); v0[6] = f2b(q1.z); v0[7] = f2b(q1.w);
  v1[0] = f2b(q2.x); v1[1] = f2b(q2.y); v1[2] = f2b(q2.z); v1[3] = f2b(q2.w);
  v1[4] = f2b(q3.x); v1[5] = f2b(q3.y); v1[6] = f2b(q3.z); v1[7] = f2b(q3.w);
  *(bf16x8*)lp = v0;
  *(bf16x8*)(lp + 8) = v1;
}

// Per-batch output slice base, dtype-aware (fl=1: bf16, fl=0: fp32).
__device__ inline char* out_slice(void* outv, int b, int fl) {
  return (char*)outv + (size_t)b * (size_t)SEQ * DIM * (fl ? 2u : 4u);
}

// ---------------------------------------------------------------------------
// Detect input dtype from w_qkv bit patterns; canonicalize qw/kw to bf16.
// ---------------------------------------------------------------------------
__global__ __launch_bounds__(256)
void detect_canon(const unsigned int* __restrict__ wbits,
                  const void* __restrict__ qw, const void* __restrict__ kw,
                  __hip_bfloat16* __restrict__ qwb,
                  __hip_bfloat16* __restrict__ kwb, int* __restrict__ flag) {
  __shared__ int cnt;
  const int t = threadIdx.x;
  if (t == 0) cnt = 0;
  __syncthreads();
  int local = 0;
  for (int i = 0; i < 4; ++i) {
    unsigned int e = (wbits[t * 4 + i] >> 7) & 0xFF;
    if (e >= 96 && e < 160) local++;
  }
  atomicAdd(&cnt, local);
  __syncthreads();
  const int f = (cnt >= 768) ? 1 : 0;  // 1 = bf16 tensors, 0 = fp32 tensors
  if (t == 0) *flag = f;
  if (t < 128)
    qwb[t] = f ? ((const __hip_bfloat16*)qw)[t]
               : __float2bfloat16(((const float*)qw)[t]);
  else
    kwb[t - 128] = f ? ((const __hip_bfloat16*)kw)[t - 128]
                     : __float2bfloat16(((const float*)kw)[t - 128]);
}

// ---------------------------------------------------------------------------
// Elementwise canonicalize a tensor to bf16 (8 elts/thread). fl=1: raw copy.
// ---------------------------------------------------------------------------
__global__ __launch_bounds__(256)
void convert_bf16(const void* __restrict__ in, __hip_bfloat16* __restrict__ out,
                  const int* __restrict__ flag) {
  const int fl = *flag;
  long i = ((long)blockIdx.x * 256 + threadIdx.x) * 8;
  if (fl) {
    *(float4*)(out + i) = *(const float4*)((const __hip_bfloat16*)in + i);
  } else {
    const float* p = (const float*)in + i;
    float4 a = ((const float4*)p)[0], b = ((const float4*)p)[1];
    bf16x8 o;
    o[0] = f2b(a.x); o[1] = f2b(a.y); o[2] = f2b(a.z); o[3] = f2b(a.w);
    o[4] = f2b(b.x); o[5] = f2b(b.y); o[6] = f2b(b.z); o[7] = f2b(b.w);
    *(bf16x8*)(out + i) = o;
  }
}

// ===========================================================================
// TIER A GEMMs (m97 structure, both operands via global_load_lds).
// ===========================================================================

__global__ __launch_bounds__(256)
void gemm_qkv_full(const __hip_bfloat16* __restrict__ A,
                   const __hip_bfloat16* __restrict__ B,
                   __hip_bfloat16* __restrict__ qk, void* __restrict__ outv,
                   const int* __restrict__ flag) {
  __shared__ __hip_bfloat16 As[128 * 32];
  __shared__ __hip_bfloat16 Bs[128 * 32];
  const int t = threadIdx.x, wave = t >> 6, lane = t & 63;
  const int quad = lane >> 4, l16 = lane & 15;
  const int wm = (wave & 1) * 64, wn = (wave >> 1) * 64;
  const long bm = (long)blockIdx.x * 128, bn = (long)blockIdx.y * 128;
  const int fl = *flag;

  f32x4 acc[4][4] = {};
  for (int k0 = 0; k0 < DIM; k0 += 32) {
    __syncthreads();
    for (int i = 0; i < 2; ++i) {
      int c = wave * 64 + lane + i * 256;
      int row = c >> 2, kc = c & 3;
      GLDS16(A + (bm + row) * DIM + k0 + kc * 8, As + (wave * 64 + i * 256) * 8);
      GLDS16(B + (bn + row) * DIM + k0 + kc * 8, Bs + (wave * 64 + i * 256) * 8);
    }
    __syncthreads();
    bf16x8 aF[4], bF[4];
    for (int mt = 0; mt < 4; ++mt)
      aF[mt] = *(const bf16x8*)(As + (wm + mt * 16 + l16) * 32 + quad * 8);
    for (int nt = 0; nt < 4; ++nt)
      bF[nt] = *(const bf16x8*)(Bs + (wn + nt * 16 + l16) * 32 + quad * 8);
    for (int mt = 0; mt < 4; ++mt)
      for (int nt = 0; nt < 4; ++nt)
        acc[mt][nt] = __builtin_amdgcn_mfma_f32_16x16x32_bf16(
            aF[mt], bF[nt], acc[mt][nt], 0, 0, 0);
  }

  if (bn < 4096) {  // Q|K block
    for (int mt = 0; mt < 4; ++mt) {
      long gr = bm + wm + mt * 16 + quad * 4;
      for (int nt = 0; nt < 4; ++nt) {
        long gc = bn + wn + nt * 16 + l16;
        for (int r = 0; r < 4; ++r)
          qk[(gr + r) * QK_LD + gc] = __float2bfloat16(acc[mt][nt][r]);
      }
    }
  } else {  // V block: transposed bf16 store into the owning batch's slice
    for (int mt = 0; mt < 4; ++mt) {
      long gr = bm + wm + mt * 16 + quad * 4;
      __hip_bfloat16* vtb = (__hip_bfloat16*)out_slice(outv, (int)(gr >> 11), fl);
      long s = gr & 2047;
      for (int nt = 0; nt < 4; ++nt) {
        long col = bn - 4096 + wn + nt * 16 + l16;  // h*128 + d
        for (int r = 0; r < 4; ++r)
          vtb[col * SEQ + s + r] = __float2bfloat16(acc[mt][nt][r]);
      }
    }
  }
}

__global__ __launch_bounds__(256)
void gemm_proj_full(const __hip_bfloat16* __restrict__ A,
                    const __hip_bfloat16* __restrict__ B,
                    void* __restrict__ outv, const int* __restrict__ flag) {
  __shared__ __hip_bfloat16 As[128 * 32];
  __shared__ __hip_bfloat16 Bs[128 * 32];
  const int t = threadIdx.x, wave = t >> 6, lane = t & 63;
  const int quad = lane >> 4, l16 = lane & 15;
  const int wm = (wave & 1) * 64, wn = (wave >> 1) * 64;
  const long bm = (long)blockIdx.x * 128, bn = (long)blockIdx.y * 128;
  const int fl = *flag;

  f32x4 acc[4][4] = {};
  for (int k0 = 0; k0 < DIM; k0 += 32) {
    __syncthreads();
    for (int i = 0; i < 2; ++i) {
      int c = wave * 64 + lane + i * 256;
      int row = c >> 2, kc = c & 3;
      GLDS16(A + (bm + row) * QK_LD + k0 + kc * 8, As + (wave * 64 + i * 256) * 8);
      GLDS16(B + (bn + row) * DIM + k0 + kc * 8, Bs + (wave * 64 + i * 256) * 8);
    }
    __syncthreads();
    bf16x8 aF[4], bF[4];
    for (int mt = 0; mt < 4; ++mt)
      aF[mt] = *(const bf16x8*)(As + (wm + mt * 16 + l16) * 32 + quad * 8);
    for (int nt = 0; nt < 4; ++nt)
      bF[nt] = *(const bf16x8*)(Bs + (wn + nt * 16 + l16) * 32 + quad * 8);
    for (int mt = 0; mt < 4; ++mt)
      for (int nt = 0; nt < 4; ++nt)
        acc[mt][nt] = __builtin_amdgcn_mfma_f32_16x16x32_bf16(
            aF[mt], bF[nt], acc[mt][nt], 0, 0, 0);
  }

  for (int mt = 0; mt < 4; ++mt) {
    long gr = bm + wm + mt * 16 + quad * 4;
    for (int nt = 0; nt < 4; ++nt) {
      long gc = bn + wn + nt * 16 + l16;
      for (int r = 0; r < 4; ++r) {
        long idx = (gr + r) * DIM + gc;
        if (fl) ((__hip_bfloat16*)outv)[idx] = __float2bfloat16(acc[mt][nt][r]);
        else    ((float*)outv)[idx] = acc[mt][nt][r];
      }
    }
  }
}

// ===========================================================================
// TIER B GEMMs (per-batch, dual staging — fallback, known-good).
// ===========================================================================

__global__ __launch_bounds__(256)
void gemm_qkv(const void* __restrict__ xin, const void* __restrict__ win,
              __hip_bfloat16* __restrict__ qk, void* __restrict__ outv,
              const int* __restrict__ flag, int b) {
  __shared__ __hip_bfloat16 As[128 * 32];
  __shared__ __hip_bfloat16 Bs[128 * 32];
  const int t = threadIdx.x, wave = t >> 6, lane = t & 63;
  const int quad = lane >> 4, l16 = lane & 15;
  const int wm = (wave & 1) * 64, wn = (wave >> 1) * 64;
  const long bm = (long)blockIdx.x * 128, bn = (long)blockIdx.y * 128;
  const int fl = *flag;
  const __hip_bfloat16* Ab = (const __hip_bfloat16*)xin + (long)b * SEQ * DIM;
  const __hip_bfloat16* Bb = (const __hip_bfloat16*)win;
  const float* Af = (const float*)xin + (long)b * SEQ * DIM;
  const float* Bf = (const float*)win;

  f32x4 acc[4][4] = {};
  for (int k0 = 0; k0 < DIM; k0 += 32) {
    __syncthreads();
    if (fl) {
      for (int i = 0; i < 2; ++i) {
        int c = wave * 64 + lane + i * 256;
        int row = c >> 2, kc = c & 3;
        GLDS16(Ab + (bm + row) * DIM + k0 + kc * 8, As + (wave * 64 + i * 256) * 8);
        GLDS16(Bb + (bn + row) * DIM + k0 + kc * 8, Bs + (wave * 64 + i * 256) * 8);
      }
    } else {
      int row = t >> 1, cb = k0 + (t & 1) * 16;
      stage16(Af + (bm + row) * DIM + cb, As + t * 16);
      stage16(Bf + (bn + row) * DIM + cb, Bs + t * 16);
    }
    __syncthreads();
    bf16x8 aF[4], bF[4];
    for (int mt = 0; mt < 4; ++mt)
      aF[mt] = *(const bf16x8*)(As + (wm + mt * 16 + l16) * 32 + quad * 8);
    for (int nt = 0; nt < 4; ++nt)
      bF[nt] = *(const bf16x8*)(Bs + (wn + nt * 16 + l16) * 32 + quad * 8);
    for (int mt = 0; mt < 4; ++mt)
      for (int nt = 0; nt < 4; ++nt)
        acc[mt][nt] = __builtin_amdgcn_mfma_f32_16x16x32_bf16(
            aF[mt], bF[nt], acc[mt][nt], 0, 0, 0);
  }

  if (bn < 4096) {
    for (int mt = 0; mt < 4; ++mt) {
      long gr = bm + wm + mt * 16 + quad * 4;
      for (int nt = 0; nt < 4; ++nt) {
        long gc = bn + wn + nt * 16 + l16;
        for (int r = 0; r < 4; ++r)
          qk[(gr + r) * QK_LD + gc] = __float2bfloat16(acc[mt][nt][r]);
      }
    }
  } else {
    __hip_bfloat16* vtb = (__hip_bfloat16*)out_slice(outv, b, fl);
    for (int mt = 0; mt < 4; ++mt) {
      long gr = bm + wm + mt * 16 + quad * 4;
      for (int nt = 0; nt < 4; ++nt) {
        long col = bn - 4096 + wn + nt * 16 + l16;
        for (int r = 0; r < 4; ++r)
          vtb[col * SEQ + gr + r] = __float2bfloat16(acc[mt][nt][r]);
      }
    }
  }
}

__global__ __launch_bounds__(256)
void gemm_proj(const __hip_bfloat16* __restrict__ A, const void* __restrict__ win,
               void* __restrict__ outv, const int* __restrict__ flag, int b) {
  __shared__ __hip_bfloat16 As[128 * 32];
  __shared__ __hip_bfloat16 Bs[128 * 32];
  const int t = threadIdx.x, wave = t >> 6, lane = t & 63;
  const int quad = lane >> 4, l16 = lane & 15;
  const int wm = (wave & 1) * 64, wn = (wave >> 1) * 64;
  const long bm = (long)blockIdx.x * 128, bn = (long)blockIdx.y * 128;
  const int fl = *flag;
  const __hip_bfloat16* Bb = (const __hip_bfloat16*)win;
  const float* Bf = (const float*)win;

  f32x4 acc[4][4] = {};
  for (int k0 = 0; k0 < DIM; k0 += 32) {
    __syncthreads();
    for (int i = 0; i < 2; ++i) {
      int c = wave * 64 + lane + i * 256;
      int row = c >> 2, kc = c & 3;
      GLDS16(A + (bm + row) * QK_LD + k0 + kc * 8, As + (wave * 64 + i * 256) * 8);
    }
    if (fl) {
      for (int i = 0; i < 2; ++i) {
        int c = wave * 64 + lane + i * 256;
        int row = c >> 2, kc = c & 3;
        GLDS16(Bb + (bn + row) * DIM + k0 + kc * 8, Bs + (wave * 64 + i * 256) * 8);
      }
    } else {
      int row = t >> 1, cb = k0 + (t & 1) * 16;
      stage16(Bf + (bn + row) * DIM + cb, Bs + t * 16);
    }
    __syncthreads();
    bf16x8 aF[4], bF[4];
    for (int mt = 0; mt < 4; ++mt)
      aF[mt] = *(const bf16x8*)(As + (wm + mt * 16 + l16) * 32 + quad * 8);
    for (int nt = 0; nt < 4; ++nt)
      bF[nt] = *(const bf16x8*)(Bs + (wn + nt * 16 + l16) * 32 + quad * 8);
    for (int mt = 0; mt < 4; ++mt)
      for (int nt = 0; nt < 4; ++nt)
        acc[mt][nt] = __builtin_amdgcn_mfma_f32_16x16x32_bf16(
            aF[mt], bF[nt], acc[mt][nt], 0, 0, 0);
  }

  char* Cb = out_slice(outv, b, fl);
  for (int mt = 0; mt < 4; ++mt) {
    long gr = bm + wm + mt * 16 + quad * 4;
    for (int nt = 0; nt < 4; ++nt) {
      long gc = bn + wn + nt * 16 + l16;
      for (int r = 0; r < 4; ++r) {
        long idx = (gr + r) * DIM + gc;
        if (fl) ((__hip_bfloat16*)Cb)[idx] = __float2bfloat16(acc[mt][nt][r]);
        else    ((float*)Cb)[idx] = acc[mt][nt][r];
      }
    }
  }
}

// ===========================================================================
// Shared kernels.
// ===========================================================================

// Per-row RMSNorm + RoPE, vectorized: lane loads uint (2 bf16), shfl
// redistributes to the (d, d+64) RoPE pairing, inverse shfl scatters back.
__global__ __launch_bounds__(256)
void norm_rope(__hip_bfloat16* __restrict__ qk,
               const __hip_bfloat16* __restrict__ qwb,
               const __hip_bfloat16* __restrict__ kwb) {
  const int wave = threadIdx.x >> 6, lane = threadIdx.x & 63;
  const int gid = blockIdx.x * 4 + wave;
  const int h = gid & 15, tt = (gid >> 4) & 1, row = gid >> 5;
  const int s = row & 2047;

  __hip_bfloat16* p = qk + (long)row * QK_LD + tt * DIM + h * HD;
  unsigned int u = ((const unsigned int*)p)[lane];  // elems (2l, 2l+1)

  // gather pair (d=lane, d=lane+64)
  unsigned int x = (unsigned int)__shfl((int)u, lane >> 1);
  unsigned int y = (unsigned int)__shfl((int)u, 32 + (lane >> 1));
  float v1 = __uint_as_float((lane & 1) ? (x & 0xFFFF0000u) : (x << 16));
  float v2 = __uint_as_float((lane & 1) ? (y & 0xFFFF0000u) : (y << 16));

  float ss = v1 * v1 + v2 * v2;
  for (int off = 1; off < 64; off <<= 1) ss += __shfl_xor(ss, off);
  float inv = rsqrtf(ss * (1.0f / 128.0f) + 1e-6f);

  const __hip_bfloat16* w = tt ? kwb : qwb;
  float n1 = v1 * inv * __bfloat162float(w[lane]);
  float n2 = v2 * inv * __bfloat162float(w[lane + 64]);

  float freq = exp2f(-5.0f * (float)lane * (1.0f / 64.0f));
  float ang = (float)s * freq;
  float c = cosf(ang), sn = sinf(ang);
  float r1 = n1 * c - n2 * sn;  // elem d = lane
  float r2 = n2 * c + n1 * sn;  // elem d = lane + 64

  // scatter back: lane stores elems (2l, 2l+1)
  float z1lo = __shfl(r1, (2 * lane) & 63), z2lo = __shfl(r2, (2 * lane) & 63);
  float z1hi = __shfl(r1, (2 * lane + 1) & 63), z2hi = __shfl(r2, (2 * lane + 1) & 63);
  float lo = (lane < 32) ? z1lo : z2lo;
  float hi = (lane < 32) ? z1hi : z2hi;
  unsigned int ou = (unsigned int)(unsigned short)f2b(lo) |
                    ((unsigned int)(unsigned short)f2b(hi) << 16);
  ((unsigned int*)p)[lane] = ou;
}

// ---------------------------------------------------------------------------
// Flash attention, non-causal. Block = 128-query tile for one (b,h);
// v5: 8 waves x 16 query rows each (512 threads). K-tiles of 64.
// Q in registers; swizzled conflict-free LDS; lean log2 softmax.
// Per-wave state: aQ 16 + oacc 32 + sacc 16 + m/l 8 = 72 VGPR floor.
// LDS 48 KB: Ks 16K [ks=4][row=64][32], Vs 16K [ks2=2][dim=128][32],
// Ps 16K [wave=8][ks2=2][row=16][32].
// ---------------------------------------------------------------------------
__global__ __launch_bounds__(512)
void flash_attn(__hip_bfloat16* __restrict__ qkbase, void* __restrict__ outv,
                const int* __restrict__ flag, int b0) {
  __shared__ __hip_bfloat16 Ks[4 * 64 * 32];
  __shared__ __hip_bfloat16 Vs[2 * 128 * 32];
  __shared__ __hip_bfloat16 Ps[8][2 * 16 * 32];

  const int t = threadIdx.x, wave = t >> 6, lane = t & 63;
  const int quad = lane >> 4, l16 = lane & 15;
  // swizzled 8-elem slot for all fragment reads (row bits 1:2 come from l16)
  const int swz = (quad ^ ((l16 >> 1) & 3)) * 8;
  const int q0 = blockIdx.x * 128, h = blockIdx.y;
  const int b = b0 + blockIdx.z;
  const int fl = *flag;
  __hip_bfloat16* qk = qkbase + (long)blockIdx.z * SEQ * QK_LD;
  __hip_bfloat16* Qg = qk + h * HD;
  const __hip_bfloat16* Kg = Qg + DIM;
  const __hip_bfloat16* Vt =
      (const __hip_bfloat16*)out_slice(outv, b, fl) + (long)h * HD * SEQ;

  // Q fragments in registers: rows q0 + wave*16 + l16
  bf16x8 aQ[4];
#pragma unroll
  for (int ks = 0; ks < 4; ++ks)
    aQ[ks] = *(const bf16x8*)(Qg +
        (long)(q0 + wave * 16 + l16) * QK_LD + ks * 32 + quad * 8);

  f32x4 oacc[8] = {};
  float m_run[4], l_run[4];  // per-lane PARTIAL l sums (4 keys/lane)
#pragma unroll
  for (int r = 0; r < 4; ++r) { m_run[r] = -1e30f; l_run[r] = 0.0f; }

  for (int j0 = 0; j0 < SEQ; j0 += 64) {
    __syncthreads();  // all waves done reading Ks/Vs of previous tile
    // stage K-tile: linear LDS dest, swizzled GLOBAL source (rule 21)
#pragma unroll
    for (int i = 0; i < 2; ++i) {
      int f = t + i * 512;                          // [0,1024) 16B chunks
      int kk = f & 3, row = (f >> 2) & 63, ks = f >> 8;
      GLDS16(Kg + (long)(j0 + row) * QK_LD + ks * 32 + (kk ^ ((row >> 1) & 3)) * 8,
             Ks + (t + i * 512) * 8);
    }
    // stage V-tile (transposed layout), swizzled source
#pragma unroll
    for (int i = 0; i < 2; ++i) {
      int f = t + i * 512;
      int kk = f & 3, dimr = (f >> 2) & 127, ks2 = f >> 9;
      GLDS16(Vt + (long)dimr * SEQ + j0 + ks2 * 32 + (kk ^ ((dimr >> 1) & 3)) * 8,
             Vs + (t + i * 512) * 8);
    }
    __syncthreads();  // drains vmcnt (GLDS) + barrier

    // S = Q K^T: 16 rows x 64 keys per wave (swizzled reads, conflict-free)
    f32x4 sacc[4] = {};
#pragma unroll
    for (int ks = 0; ks < 4; ++ks)
#pragma unroll
      for (int nt = 0; nt < 4; ++nt) {
        bf16x8 bK = *(const bf16x8*)(Ks + (ks * 64 + nt * 16 + l16) * 32 + swz);
        sacc[nt] = __builtin_amdgcn_mfma_f32_16x16x32_bf16(
            aQ[ks], bK, sacc[nt], 0, 0, 0);
      }

    // online softmax in log2 domain; max reduced across the 16-lane quad
    __hip_bfloat16* pw = &Ps[wave][0];
#pragma unroll
    for (int r = 0; r < 4; ++r) {
      float p0 = sacc[0][r] * SC2, p1 = sacc[1][r] * SC2;
      float p2 = sacc[2][r] * SC2, p3 = sacc[3][r] * SC2;
      float mx = fmaxf(fmaxf(p0, p1), fmaxf(p2, p3));
      for (int off = 1; off < 16; off <<= 1)
        mx = fmaxf(mx, __shfl_xor(mx, off));
      // defer-max (T13): only rescale when some row grew past THR=8
      if (__any(mx > m_run[r] + 8.0f)) {
        float mnew = fmaxf(m_run[r], mx);
        float alpha = exp2f(m_run[r] - mnew);
        m_run[r] = mnew;
        l_run[r] *= alpha;
#pragma unroll
        for (int n = 0; n < 8; ++n) oacc[n][r] *= alpha;
      }
      float m = m_run[r];
      float e0 = exp2f(p0 - m), e1 = exp2f(p1 - m);
      float e2 = exp2f(p2 - m), e3 = exp2f(p3 - m);
      l_run[r] += (e0 + e1) + (e2 + e3);  // per-lane partial
      // P store: C-layout -> A-layout, swizzled, wave-private
      int rbase = (quad * 4 + r) * 32;
      int sc = (((quad * 4 + r) >> 1) & 3) << 3;
      pw[rbase + (l16 ^ sc)] = __float2bfloat16(e0);
      pw[rbase + ((l16 + 16) ^ sc)] = __float2bfloat16(e1);
      pw[512 + rbase + (l16 ^ sc)] = __float2bfloat16(e2);
      pw[512 + rbase + ((l16 + 16) ^ sc)] = __float2bfloat16(e3);
    }

    // O += P @ V  (intra-wave LDS RAW ordered by lgkmcnt, not __syncthreads)
#pragma unroll
    for (int ks2 = 0; ks2 < 2; ++ks2) {
      bf16x8 aP = *(const bf16x8*)(pw + (ks2 * 16 + l16) * 32 + swz);
#pragma unroll
      for (int n = 0; n < 8; ++n) {
        bf16x8 bV = *(const bf16x8*)(Vs + (ks2 * 128 + n * 16 + l16) * 32 + swz);
        oacc[n] = __builtin_amdgcn_mfma_f32_16x16x32_bf16(
            aP, bV, oacc[n], 0, 0, 0);
      }
    }
  }

  // epilogue: finish deferred l reduction, write O into the Q-slot region
#pragma unroll
  for (int r = 0; r < 4; ++r) {
    float l = l_run[r];
    for (int off = 1; off < 16; off <<= 1) l += __shfl_xor(l, off);
    float rl = 1.0f / l;
    long s = q0 + wave * 16 + quad * 4 + r;
    for (int n = 0; n < 8; ++n)
      qk[s * QK_LD + h * HD + n * 16 + l16] =
          __float2bfloat16(oacc[n][r] * rl);
  }
}

// ---------------------------------------------------------------------------
extern "C" void kernel_launch(void* const* d_in, const int* in_sizes, int n_in,
                              void* d_out, int out_size, void* d_ws, size_t ws_size,
                              hipStream_t stream) {
  int* flag = (int*)d_ws;
  __hip_bfloat16* qwb = (__hip_bfloat16*)((char*)d_ws + 64);
  __hip_bfloat16* kwb = qwb + 128;
  char* base = (char*)d_ws + 1024;

  detect_canon<<<1, 256, 0, stream>>>((const unsigned int*)d_in[1], d_in[3],
                                      d_in[4], qwb, kwb, flag);

  const size_t MB = 1024ull * 1024ull;
  const size_t NEED_A = 1024 + 128 * MB;

  if (ws_size >= NEED_A) {
    // ---- Tier A: full-batch bf16 path ----
    __hip_bfloat16* xb     = (__hip_bfloat16*)base;              // 32 MiB
    __hip_bfloat16* wqkvb  = (__hip_bfloat16*)(base + 32 * MB);  // 24 MiB
    __hip_bfloat16* wprojb = (__hip_bfloat16*)(base + 56 * MB);  //  8 MiB
    __hip_bfloat16* qk     = (__hip_bfloat16*)(base + 64 * MB);  // 64 MiB

    convert_bf16<<<(BSZ * SEQ * DIM) / 2048, 256, 0, stream>>>(d_in[0], xb, flag);
    convert_bf16<<<(3 * DIM * DIM) / 2048, 256, 0, stream>>>(d_in[1], wqkvb, flag);
    convert_bf16<<<(DIM * DIM) / 2048, 256, 0, stream>>>(d_in[2], wprojb, flag);

    gemm_qkv_full<<<dim3((BSZ * SEQ) / 128, (3 * DIM) / 128), 256, 0, stream>>>(
        xb, wqkvb, qk, d_out, flag);
    norm_rope<<<(BSZ * SEQ * 2 * NH) / 4, 256, 0, stream>>>(qk, qwb, kwb);
    flash_attn<<<dim3(SEQ / 128, NH, BSZ), 512, 0, stream>>>(qk, d_out, flag, 0);
    gemm_proj_full<<<dim3((BSZ * SEQ) / 128, DIM / 128), 256, 0, stream>>>(
        qk, wprojb, d_out, flag);
  } else {
    // ---- Tier B: per-batch fallback ----
    __hip_bfloat16* qk = (__hip_bfloat16*)base;  // 16 MiB, reused per batch
    for (int b = 0; b < BSZ; ++b) {
      gemm_qkv<<<dim3(SEQ / 128, (3 * DIM) / 128), 256, 0, stream>>>(
          d_in[0], d_in[1], qk, d_out, flag, b);
      norm_rope<<<(SEQ * 2 * NH) / 4, 256, 0, stream>>>(qk, qwb, kwb);
      flash_attn<<<dim3(SEQ / 128, NH, 1), 512, 0, stream>>>(qk, d_out, flag, b);
      gemm_proj<<<dim3(SEQ / 128, DIM / 128), 256, 0, stream>>>(
          qk, d_in[2], d_out, flag, b);
    }
  }
}

// Round 7
// 793.719 us; speedup vs baseline: 1.2184x; 1.0943x over previous
//
// ===========================================================================
// FlowerAttention fused pipeline (MI355X / gfx950).
//
// v6 = v5 + (a) swapped-QK^T in-register-P flash_attn, (b) T1 XCD swizzle
// on Tier-A GEMMs.
// Evidence chain: v1..v5 proved dur*MfmaUtil==const and conflicts-free ==
// conflicted at equal occupancy => LDS-ISSUE-bound (~70% of block-tile time
// = 600 LDS-pipe cyc/wave-tile x 16 waves vs 13.5k cyc measured).
// (a) removes the P LDS round-trip: swapped mfma(bK,aQ) puts S[key][query]
//     with query=l16 lane-local; P->aP via 16 ds_bpermute + selects (no
//     Ps buffer, no 16 ds_write_b16, no 2 ds_read_b128). LDS 48->32KB.
// (b) (lin%8)*chunk + lin/8 block remap, bijective (3072%8==0, 1024%8==0).
// Predicted: flash 361 -> ~300-315us (VGPR ~100-110, MfmaUtil ~19),
// GEMMs -5-10%, total ~800us.
// ===========================================================================
#include <hip/hip_runtime.h>
#include <hip/hip_bf16.h>

#define BSZ 4
#define SEQ 2048
#define DIM 2048
#define NH 16
#define HD 128
#define QK_LD 4096  // row stride of packed Q|K workspace
#define SCALE 0.08838834764831845f
// SCALE * log2(e): softmax done in log2 domain (exp2 is the native HW op)
#define SC2 0.12751742910198f

typedef __attribute__((ext_vector_type(8))) short bf16x8;
typedef __attribute__((ext_vector_type(4))) float f32x4;

// Async global->LDS, 16B per lane. LDS dest = wave-uniform base + lane*16.
#define GLDS16(g, l)                                                           \
  __builtin_amdgcn_global_load_lds(                                           \
      (const __attribute__((address_space(1))) void*)(g),                     \
      (__attribute__((address_space(3))) void*)(l), 16, 0, 0)

__device__ inline short f2b(float f) {
  __hip_bfloat16 h = __float2bfloat16(f);
  short s;
  __builtin_memcpy(&s, &h, 2);
  return s;
}

// Load 16 contiguous fp32, convert to bf16, store 32B to LDS (two b128).
__device__ inline void stage16(const float* gp, __hip_bfloat16* lp) {
  float4 q0 = ((const float4*)gp)[0], q1 = ((const float4*)gp)[1];
  float4 q2 = ((const float4*)gp)[2], q3 = ((const float4*)gp)[3];
  bf16x8 v0, v1;
  v0[0] = f2b(q0.x); v0[1] = f2b(q0.y); v0[2] = f2b(q0.z); v0[3] = f2b(q0.w);
  v0[4] = f2b(q1.x); v0[5] = f2b(q1.y); v0[6] = f2b(q1.z); v0[7] = f2b(q1.w);
  v1[0] = f2b(q2.x); v1[1] = f2b(q2.y); v1[2] = f2b(q2.z); v1[3] = f2b(q2.w);
  v1[4] = f2b(q3.x); v1[5] = f2b(q3.y); v1[6] = f2b(q3.z); v1[7] = f2b(q3.w);
  *(bf16x8*)lp = v0;
  *(bf16x8*)(lp + 8) = v1;
}

// Per-batch output slice base, dtype-aware (fl=1: bf16, fl=0: fp32).
__device__ inline char* out_slice(void* outv, int b, int fl) {
  return (char*)outv + (size_t)b * (size_t)SEQ * DIM * (fl ? 2u : 4u);
}

// T1: XCD-aware bijective block remap (requires nwg % 8 == 0).
__device__ inline void xcd_remap(long& bm, long& bn) {
  int nwg = gridDim.x * gridDim.y;
  int lin = blockIdx.y * gridDim.x + blockIdx.x;
  int cpx = nwg >> 3;
  lin = (lin & 7) * cpx + (lin >> 3);
  bm = (long)(lin % gridDim.x) * 128;
  bn = (long)(lin / gridDim.x) * 128;
}

// ---------------------------------------------------------------------------
// Detect input dtype from w_qkv bit patterns; canonicalize qw/kw to bf16.
// ---------------------------------------------------------------------------
__global__ __launch_bounds__(256)
void detect_canon(const unsigned int* __restrict__ wbits,
                  const void* __restrict__ qw, const void* __restrict__ kw,
                  __hip_bfloat16* __restrict__ qwb,
                  __hip_bfloat16* __restrict__ kwb, int* __restrict__ flag) {
  __shared__ int cnt;
  const int t = threadIdx.x;
  if (t == 0) cnt = 0;
  __syncthreads();
  int local = 0;
  for (int i = 0; i < 4; ++i) {
    unsigned int e = (wbits[t * 4 + i] >> 7) & 0xFF;
    if (e >= 96 && e < 160) local++;
  }
  atomicAdd(&cnt, local);
  __syncthreads();
  const int f = (cnt >= 768) ? 1 : 0;  // 1 = bf16 tensors, 0 = fp32 tensors
  if (t == 0) *flag = f;
  if (t < 128)
    qwb[t] = f ? ((const __hip_bfloat16*)qw)[t]
               : __float2bfloat16(((const float*)qw)[t]);
  else
    kwb[t - 128] = f ? ((const __hip_bfloat16*)kw)[t - 128]
                     : __float2bfloat16(((const float*)kw)[t - 128]);
}

// ---------------------------------------------------------------------------
// Elementwise canonicalize a tensor to bf16 (8 elts/thread). fl=1: raw copy.
// ---------------------------------------------------------------------------
__global__ __launch_bounds__(256)
void convert_bf16(const void* __restrict__ in, __hip_bfloat16* __restrict__ out,
                  const int* __restrict__ flag) {
  const int fl = *flag;
  long i = ((long)blockIdx.x * 256 + threadIdx.x) * 8;
  if (fl) {
    *(float4*)(out + i) = *(const float4*)((const __hip_bfloat16*)in + i);
  } else {
    const float* p = (const float*)in + i;
    float4 a = ((const float4*)p)[0], b = ((const float4*)p)[1];
    bf16x8 o;
    o[0] = f2b(a.x); o[1] = f2b(a.y); o[2] = f2b(a.z); o[3] = f2b(a.w);
    o[4] = f2b(b.x); o[5] = f2b(b.y); o[6] = f2b(b.z); o[7] = f2b(b.w);
    *(bf16x8*)(out + i) = o;
  }
}

// ===========================================================================
// TIER A GEMMs (m97 structure, both operands via global_load_lds).
// ===========================================================================

__global__ __launch_bounds__(256)
void gemm_qkv_full(const __hip_bfloat16* __restrict__ A,
                   const __hip_bfloat16* __restrict__ B,
                   __hip_bfloat16* __restrict__ qk, void* __restrict__ outv,
                   const int* __restrict__ flag) {
  __shared__ __hip_bfloat16 As[128 * 32];
  __shared__ __hip_bfloat16 Bs[128 * 32];
  const int t = threadIdx.x, wave = t >> 6, lane = t & 63;
  const int quad = lane >> 4, l16 = lane & 15;
  const int wm = (wave & 1) * 64, wn = (wave >> 1) * 64;
  long bm, bn;
  xcd_remap(bm, bn);
  const int fl = *flag;

  f32x4 acc[4][4] = {};
  for (int k0 = 0; k0 < DIM; k0 += 32) {
    __syncthreads();
    for (int i = 0; i < 2; ++i) {
      int c = wave * 64 + lane + i * 256;
      int row = c >> 2, kc = c & 3;
      GLDS16(A + (bm + row) * DIM + k0 + kc * 8, As + (wave * 64 + i * 256) * 8);
      GLDS16(B + (bn + row) * DIM + k0 + kc * 8, Bs + (wave * 64 + i * 256) * 8);
    }
    __syncthreads();
    bf16x8 aF[4], bF[4];
    for (int mt = 0; mt < 4; ++mt)
      aF[mt] = *(const bf16x8*)(As + (wm + mt * 16 + l16) * 32 + quad * 8);
    for (int nt = 0; nt < 4; ++nt)
      bF[nt] = *(const bf16x8*)(Bs + (wn + nt * 16 + l16) * 32 + quad * 8);
    for (int mt = 0; mt < 4; ++mt)
      for (int nt = 0; nt < 4; ++nt)
        acc[mt][nt] = __builtin_amdgcn_mfma_f32_16x16x32_bf16(
            aF[mt], bF[nt], acc[mt][nt], 0, 0, 0);
  }

  if (bn < 4096) {  // Q|K block
    for (int mt = 0; mt < 4; ++mt) {
      long gr = bm + wm + mt * 16 + quad * 4;
      for (int nt = 0; nt < 4; ++nt) {
        long gc = bn + wn + nt * 16 + l16;
        for (int r = 0; r < 4; ++r)
          qk[(gr + r) * QK_LD + gc] = __float2bfloat16(acc[mt][nt][r]);
      }
    }
  } else {  // V block: transposed bf16 store into the owning batch's slice
    for (int mt = 0; mt < 4; ++mt) {
      long gr = bm + wm + mt * 16 + quad * 4;
      __hip_bfloat16* vtb = (__hip_bfloat16*)out_slice(outv, (int)(gr >> 11), fl);
      long s = gr & 2047;
      for (int nt = 0; nt < 4; ++nt) {
        long col = bn - 4096 + wn + nt * 16 + l16;  // h*128 + d
        for (int r = 0; r < 4; ++r)
          vtb[col * SEQ + s + r] = __float2bfloat16(acc[mt][nt][r]);
      }
    }
  }
}

__global__ __launch_bounds__(256)
void gemm_proj_full(const __hip_bfloat16* __restrict__ A,
                    const __hip_bfloat16* __restrict__ B,
                    void* __restrict__ outv, const int* __restrict__ flag) {
  __shared__ __hip_bfloat16 As[128 * 32];
  __shared__ __hip_bfloat16 Bs[128 * 32];
  const int t = threadIdx.x, wave = t >> 6, lane = t & 63;
  const int quad = lane >> 4, l16 = lane & 15;
  const int wm = (wave & 1) * 64, wn = (wave >> 1) * 64;
  long bm, bn;
  xcd_remap(bm, bn);
  const int fl = *flag;

  f32x4 acc[4][4] = {};
  for (int k0 = 0; k0 < DIM; k0 += 32) {
    __syncthreads();
    for (int i = 0; i < 2; ++i) {
      int c = wave * 64 + lane + i * 256;
      int row = c >> 2, kc = c & 3;
      GLDS16(A + (bm + row) * QK_LD + k0 + kc * 8, As + (wave * 64 + i * 256) * 8);
      GLDS16(B + (bn + row) * DIM + k0 + kc * 8, Bs + (wave * 64 + i * 256) * 8);
    }
    __syncthreads();
    bf16x8 aF[4], bF[4];
    for (int mt = 0; mt < 4; ++mt)
      aF[mt] = *(const bf16x8*)(As + (wm + mt * 16 + l16) * 32 + quad * 8);
    for (int nt = 0; nt < 4; ++nt)
      bF[nt] = *(const bf16x8*)(Bs + (wn + nt * 16 + l16) * 32 + quad * 8);
    for (int mt = 0; mt < 4; ++mt)
      for (int nt = 0; nt < 4; ++nt)
        acc[mt][nt] = __builtin_amdgcn_mfma_f32_16x16x32_bf16(
            aF[mt], bF[nt], acc[mt][nt], 0, 0, 0);
  }

  for (int mt = 0; mt < 4; ++mt) {
    long gr = bm + wm + mt * 16 + quad * 4;
    for (int nt = 0; nt < 4; ++nt) {
      long gc = bn + wn + nt * 16 + l16;
      for (int r = 0; r < 4; ++r) {
        long idx = (gr + r) * DIM + gc;
        if (fl) ((__hip_bfloat16*)outv)[idx] = __float2bfloat16(acc[mt][nt][r]);
        else    ((float*)outv)[idx] = acc[mt][nt][r];
      }
    }
  }
}

// ===========================================================================
// TIER B GEMMs (per-batch, dual staging — fallback, known-good).
// ===========================================================================

__global__ __launch_bounds__(256)
void gemm_qkv(const void* __restrict__ xin, const void* __restrict__ win,
              __hip_bfloat16* __restrict__ qk, void* __restrict__ outv,
              const int* __restrict__ flag, int b) {
  __shared__ __hip_bfloat16 As[128 * 32];
  __shared__ __hip_bfloat16 Bs[128 * 32];
  const int t = threadIdx.x, wave = t >> 6, lane = t & 63;
  const int quad = lane >> 4, l16 = lane & 15;
  const int wm = (wave & 1) * 64, wn = (wave >> 1) * 64;
  const long bm = (long)blockIdx.x * 128, bn = (long)blockIdx.y * 128;
  const int fl = *flag;
  const __hip_bfloat16* Ab = (const __hip_bfloat16*)xin + (long)b * SEQ * DIM;
  const __hip_bfloat16* Bb = (const __hip_bfloat16*)win;
  const float* Af = (const float*)xin + (long)b * SEQ * DIM;
  const float* Bf = (const float*)win;

  f32x4 acc[4][4] = {};
  for (int k0 = 0; k0 < DIM; k0 += 32) {
    __syncthreads();
    if (fl) {
      for (int i = 0; i < 2; ++i) {
        int c = wave * 64 + lane + i * 256;
        int row = c >> 2, kc = c & 3;
        GLDS16(Ab + (bm + row) * DIM + k0 + kc * 8, As + (wave * 64 + i * 256) * 8);
        GLDS16(Bb + (bn + row) * DIM + k0 + kc * 8, Bs + (wave * 64 + i * 256) * 8);
      }
    } else {
      int row = t >> 1, cb = k0 + (t & 1) * 16;
      stage16(Af + (bm + row) * DIM + cb, As + t * 16);
      stage16(Bf + (bn + row) * DIM + cb, Bs + t * 16);
    }
    __syncthreads();
    bf16x8 aF[4], bF[4];
    for (int mt = 0; mt < 4; ++mt)
      aF[mt] = *(const bf16x8*)(As + (wm + mt * 16 + l16) * 32 + quad * 8);
    for (int nt = 0; nt < 4; ++nt)
      bF[nt] = *(const bf16x8*)(Bs + (wn + nt * 16 + l16) * 32 + quad * 8);
    for (int mt = 0; mt < 4; ++mt)
      for (int nt = 0; nt < 4; ++nt)
        acc[mt][nt] = __builtin_amdgcn_mfma_f32_16x16x32_bf16(
            aF[mt], bF[nt], acc[mt][nt], 0, 0, 0);
  }

  if (bn < 4096) {
    for (int mt = 0; mt < 4; ++mt) {
      long gr = bm + wm + mt * 16 + quad * 4;
      for (int nt = 0; nt < 4; ++nt) {
        long gc = bn + wn + nt * 16 + l16;
        for (int r = 0; r < 4; ++r)
          qk[(gr + r) * QK_LD + gc] = __float2bfloat16(acc[mt][nt][r]);
      }
    }
  } else {
    __hip_bfloat16* vtb = (__hip_bfloat16*)out_slice(outv, b, fl);
    for (int mt = 0; mt < 4; ++mt) {
      long gr = bm + wm + mt * 16 + quad * 4;
      for (int nt = 0; nt < 4; ++nt) {
        long col = bn - 4096 + wn + nt * 16 + l16;
        for (int r = 0; r < 4; ++r)
          vtb[col * SEQ + gr + r] = __float2bfloat16(acc[mt][nt][r]);
      }
    }
  }
}

__global__ __launch_bounds__(256)
void gemm_proj(const __hip_bfloat16* __restrict__ A, const void* __restrict__ win,
               void* __restrict__ outv, const int* __restrict__ flag, int b) {
  __shared__ __hip_bfloat16 As[128 * 32];
  __shared__ __hip_bfloat16 Bs[128 * 32];
  const int t = threadIdx.x, wave = t >> 6, lane = t & 63;
  const int quad = lane >> 4, l16 = lane & 15;
  const int wm = (wave & 1) * 64, wn = (wave >> 1) * 64;
  const long bm = (long)blockIdx.x * 128, bn = (long)blockIdx.y * 128;
  const int fl = *flag;
  const __hip_bfloat16* Bb = (const __hip_bfloat16*)win;
  const float* Bf = (const float*)win;

  f32x4 acc[4][4] = {};
  for (int k0 = 0; k0 < DIM; k0 += 32) {
    __syncthreads();
    for (int i = 0; i < 2; ++i) {
      int c = wave * 64 + lane + i * 256;
      int row = c >> 2, kc = c & 3;
      GLDS16(A + (bm + row) * QK_LD + k0 + kc * 8, As + (wave * 64 + i * 256) * 8);
    }
    if (fl) {
      for (int i = 0; i < 2; ++i) {
        int c = wave * 64 + lane + i * 256;
        int row = c >> 2, kc = c & 3;
        GLDS16(Bb + (bn + row) * DIM + k0 + kc * 8, Bs + (wave * 64 + i * 256) * 8);
      }
    } else {
      int row = t >> 1, cb = k0 + (t & 1) * 16;
      stage16(Bf + (bn + row) * DIM + cb, Bs + t * 16);
    }
    __syncthreads();
    bf16x8 aF[4], bF[4];
    for (int mt = 0; mt < 4; ++mt)
      aF[mt] = *(const bf16x8*)(As + (wm + mt * 16 + l16) * 32 + quad * 8);
    for (int nt = 0; nt < 4; ++nt)
      bF[nt] = *(const bf16x8*)(Bs + (wn + nt * 16 + l16) * 32 + quad * 8);
    for (int mt = 0; mt < 4; ++mt)
      for (int nt = 0; nt < 4; ++nt)
        acc[mt][nt] = __builtin_amdgcn_mfma_f32_16x16x32_bf16(
            aF[mt], bF[nt], acc[mt][nt], 0, 0, 0);
  }

  char* Cb = out_slice(outv, b, fl);
  for (int mt = 0; mt < 4; ++mt) {
    long gr = bm + wm + mt * 16 + quad * 4;
    for (int nt = 0; nt < 4; ++nt) {
      long gc = bn + wn + nt * 16 + l16;
      for (int r = 0; r < 4; ++r) {
        long idx = (gr + r) * DIM + gc;
        if (fl) ((__hip_bfloat16*)Cb)[idx] = __float2bfloat16(acc[mt][nt][r]);
        else    ((float*)Cb)[idx] = acc[mt][nt][r];
      }
    }
  }
}

// ===========================================================================
// Shared kernels.
// ===========================================================================

// Per-row RMSNorm + RoPE, vectorized: lane loads uint (2 bf16), shfl
// redistributes to the (d, d+64) RoPE pairing, inverse shfl scatters back.
__global__ __launch_bounds__(256)
void norm_rope(__hip_bfloat16* __restrict__ qk,
               const __hip_bfloat16* __restrict__ qwb,
               const __hip_bfloat16* __restrict__ kwb) {
  const int wave = threadIdx.x >> 6, lane = threadIdx.x & 63;
  const int gid = blockIdx.x * 4 + wave;
  const int h = gid & 15, tt = (gid >> 4) & 1, row = gid >> 5;
  const int s = row & 2047;

  __hip_bfloat16* p = qk + (long)row * QK_LD + tt * DIM + h * HD;
  unsigned int u = ((const unsigned int*)p)[lane];  // elems (2l, 2l+1)

  // gather pair (d=lane, d=lane+64)
  unsigned int x = (unsigned int)__shfl((int)u, lane >> 1);
  unsigned int y = (unsigned int)__shfl((int)u, 32 + (lane >> 1));
  float v1 = __uint_as_float((lane & 1) ? (x & 0xFFFF0000u) : (x << 16));
  float v2 = __uint_as_float((lane & 1) ? (y & 0xFFFF0000u) : (y << 16));

  float ss = v1 * v1 + v2 * v2;
  for (int off = 1; off < 64; off <<= 1) ss += __shfl_xor(ss, off);
  float inv = rsqrtf(ss * (1.0f / 128.0f) + 1e-6f);

  const __hip_bfloat16* w = tt ? kwb : qwb;
  float n1 = v1 * inv * __bfloat162float(w[lane]);
  float n2 = v2 * inv * __bfloat162float(w[lane + 64]);

  float freq = exp2f(-5.0f * (float)lane * (1.0f / 64.0f));
  float ang = (float)s * freq;
  float c = cosf(ang), sn = sinf(ang);
  float r1 = n1 * c - n2 * sn;  // elem d = lane
  float r2 = n2 * c + n1 * sn;  // elem d = lane + 64

  // scatter back: lane stores elems (2l, 2l+1)
  float z1lo = __shfl(r1, (2 * lane) & 63), z2lo = __shfl(r2, (2 * lane) & 63);
  float z1hi = __shfl(r1, (2 * lane + 1) & 63), z2hi = __shfl(r2, (2 * lane + 1) & 63);
  float lo = (lane < 32) ? z1lo : z2lo;
  float hi = (lane < 32) ? z1hi : z2hi;
  unsigned int ou = (unsigned int)(unsigned short)f2b(lo) |
                    ((unsigned int)(unsigned short)f2b(hi) << 16);
  ((unsigned int*)p)[lane] = ou;
}

// ---------------------------------------------------------------------------
// Flash attention, non-causal. Block = 128-query tile for one (b,h);
// 8 waves x 16 query rows (512 threads). K-tiles of 64.
// v6: SWAPPED QK^T: sacc[nt] = mfma(bK, aQ) -> sacc rows = keys
// (nt*16+quad*4+r), cols = queries (l16). Softmax is lane-local per query
// l16 (15 fmax + 2 shfl). P converted to bf16 in-register and exchanged
// across quads (16 ds_bpermute + selects) into PV A-fragments aP[ks2]:
// lane (quad,l16) needs P[query l16][keys ks2*32+quad*8+j]; source of word
// (h, s-pair b) = W[2ks2+(quad>>1)][h] at lane ((quad&1)*2+b)*16 + l16.
// No Ps buffer: LDS = Ks 16K + Vs 16K = 32 KB.
// ---------------------------------------------------------------------------
__global__ __launch_bounds__(512)
void flash_attn(__hip_bfloat16* __restrict__ qkbase, void* __restrict__ outv,
                const int* __restrict__ flag, int b0) {
  __shared__ __hip_bfloat16 Ks[4 * 64 * 32];
  __shared__ __hip_bfloat16 Vs[2 * 128 * 32];

  const int t = threadIdx.x, wave = t >> 6, lane = t & 63;
  const int quad = lane >> 4, l16 = lane & 15;
  // swizzled 8-elem slot for all fragment reads (row bits 1:2 come from l16)
  const int swz = (quad ^ ((l16 >> 1) & 3)) * 8;
  const int q0 = blockIdx.x * 128, h = blockIdx.y;
  const int b = b0 + blockIdx.z;
  const int fl = *flag;
  __hip_bfloat16* qk = qkbase + (long)blockIdx.z * SEQ * QK_LD;
  __hip_bfloat16* Qg = qk + h * HD;
  const __hip_bfloat16* Kg = Qg + DIM;
  const __hip_bfloat16* Vt =
      (const __hip_bfloat16*)out_slice(outv, b, fl) + (long)h * HD * SEQ;

  // exchange source lanes (same l16, quad-pair determined by own quad&1)
  const int srcA = ((lane >> 4) & 1) * 32 + l16;  // quad (quad&1)*2
  const int srcB = srcA + 16;                     // quad (quad&1)*2 + 1
  const bool hiq = (quad >= 2);

  // Q fragments in registers: rows q0 + wave*16 + l16
  bf16x8 aQ[4];
#pragma unroll
  for (int ks = 0; ks < 4; ++ks)
    aQ[ks] = *(const bf16x8*)(Qg +
        (long)(q0 + wave * 16 + l16) * QK_LD + ks * 32 + quad * 8);

  f32x4 oacc[8] = {};
  float m_run = -1e30f, l_run = 0.0f;  // per-lane: query l16, own 16 keys

  for (int j0 = 0; j0 < SEQ; j0 += 64) {
    __syncthreads();  // all waves done reading Ks/Vs of previous tile
    // stage K-tile: linear LDS dest, swizzled GLOBAL source (rule 21)
#pragma unroll
    for (int i = 0; i < 2; ++i) {
      int f = t + i * 512;                          // [0,1024) 16B chunks
      int kk = f & 3, row = (f >> 2) & 63, ks = f >> 8;
      GLDS16(Kg + (long)(j0 + row) * QK_LD + ks * 32 + (kk ^ ((row >> 1) & 3)) * 8,
             Ks + (t + i * 512) * 8);
    }
    // stage V-tile (transposed layout), swizzled source
#pragma unroll
    for (int i = 0; i < 2; ++i) {
      int f = t + i * 512;
      int kk = f & 3, dimr = (f >> 2) & 127, ks2 = f >> 9;
      GLDS16(Vt + (long)dimr * SEQ + j0 + ks2 * 32 + (kk ^ ((dimr >> 1) & 3)) * 8,
             Vs + (t + i * 512) * 8);
    }
    __syncthreads();  // drains vmcnt (GLDS) + barrier

    // S^T = K Q^T: sacc[nt][r] = S[key nt*16+quad*4+r][query l16]
    f32x4 sacc[4] = {};
#pragma unroll
    for (int ks = 0; ks < 4; ++ks)
#pragma unroll
      for (int nt = 0; nt < 4; ++nt) {
        bf16x8 bK = *(const bf16x8*)(Ks + (ks * 64 + nt * 16 + l16) * 32 + swz);
        sacc[nt] = __builtin_amdgcn_mfma_f32_16x16x32_bf16(
            bK, aQ[ks], sacc[nt], 0, 0, 0);
      }

    // lane-local softmax (query l16, 16 keys per lane)
    float p[16];
#pragma unroll
    for (int nt = 0; nt < 4; ++nt)
#pragma unroll
      for (int r = 0; r < 4; ++r) p[nt * 4 + r] = sacc[nt][r] * SC2;
    float mx = p[0];
#pragma unroll
    for (int i = 1; i < 16; ++i) mx = fmaxf(mx, p[i]);
    mx = fmaxf(mx, __shfl_xor(mx, 16));
    mx = fmaxf(mx, __shfl_xor(mx, 32));
    // defer-max (T13): rescale only when some query's max grew past THR=8
    if (__any(mx > m_run + 8.0f)) {
      float mnew = fmaxf(m_run, mx);
      float alpha = exp2f(m_run - mnew);
      m_run = mnew;
      l_run *= alpha;
      // oacc rows are queries quad*4+r: fetch that query's alpha
#pragma unroll
      for (int r = 0; r < 4; ++r) {
        float ar = __shfl(alpha, quad * 20 + r);
#pragma unroll
        for (int n = 0; n < 8; ++n) oacc[n][r] *= ar;
      }
    }
    // P = exp2(p - m); pack to bf16 pairs W[nt][h] (keys ascending)
    unsigned int W[4][2];
    float sum = 0.0f;
#pragma unroll
    for (int nt = 0; nt < 4; ++nt) {
      float e0 = exp2f(p[nt * 4 + 0] - m_run), e1 = exp2f(p[nt * 4 + 1] - m_run);
      float e2 = exp2f(p[nt * 4 + 2] - m_run), e3 = exp2f(p[nt * 4 + 3] - m_run);
      sum += (e0 + e1) + (e2 + e3);
      W[nt][0] = (unsigned int)(unsigned short)f2b(e0) |
                 ((unsigned int)(unsigned short)f2b(e1) << 16);
      W[nt][1] = (unsigned int)(unsigned short)f2b(e2) |
                 ((unsigned int)(unsigned short)f2b(e3) << 16);
    }
    l_run += sum;

    // exchange: aP[ks2] word w = W[2ks2+(quad>>1)][w&1] from lane
    // ((quad&1)*2 + (w>>1))*16 + l16
    union { unsigned int u[4]; bf16x8 v; } ap[2];
#pragma unroll
    for (int ks2 = 0; ks2 < 2; ++ks2) {
#pragma unroll
      for (int hh = 0; hh < 2; ++hh) {
        unsigned int lo0 = (unsigned int)__shfl((int)W[2 * ks2][hh], srcA);
        unsigned int hi0 = (unsigned int)__shfl((int)W[2 * ks2 + 1][hh], srcA);
        unsigned int lo1 = (unsigned int)__shfl((int)W[2 * ks2][hh], srcB);
        unsigned int hi1 = (unsigned int)__shfl((int)W[2 * ks2 + 1][hh], srcB);
        ap[ks2].u[hh] = hiq ? hi0 : lo0;
        ap[ks2].u[2 + hh] = hiq ? hi1 : lo1;
      }
    }

    // O += P @ V: A = aP (rows=queries), B = V (rows=dims)
#pragma unroll
    for (int ks2 = 0; ks2 < 2; ++ks2) {
      bf16x8 aP = ap[ks2].v;
#pragma unroll
      for (int n = 0; n < 8; ++n) {
        bf16x8 bV = *(const bf16x8*)(Vs + (ks2 * 128 + n * 16 + l16) * 32 + swz);
        oacc[n] = __builtin_amdgcn_mfma_f32_16x16x32_bf16(
            aP, bV, oacc[n], 0, 0, 0);
      }
    }
  }

  // epilogue: total l per query (reduce over the 4 quads), write O
  float l = l_run;
  l += __shfl_xor(l, 16);
  l += __shfl_xor(l, 32);
  float rl = 1.0f / l;  // for query l16
#pragma unroll
  for (int r = 0; r < 4; ++r) {
    float rlr = __shfl(rl, quad * 20 + r);  // for query quad*4+r
    long s = q0 + wave * 16 + quad * 4 + r;
    for (int n = 0; n < 8; ++n)
      qk[s * QK_LD + h * HD + n * 16 + l16] =
          __float2bfloat16(oacc[n][r] * rlr);
  }
}

// ---------------------------------------------------------------------------
extern "C" void kernel_launch(void* const* d_in, const int* in_sizes, int n_in,
                              void* d_out, int out_size, void* d_ws, size_t ws_size,
                              hipStream_t stream) {
  int* flag = (int*)d_ws;
  __hip_bfloat16* qwb = (__hip_bfloat16*)((char*)d_ws + 64);
  __hip_bfloat16* kwb = qwb + 128;
  char* base = (char*)d_ws + 1024;

  detect_canon<<<1, 256, 0, stream>>>((const unsigned int*)d_in[1], d_in[3],
                                      d_in[4], qwb, kwb, flag);

  const size_t MB = 1024ull * 1024ull;
  const size_t NEED_A = 1024 + 128 * MB;

  if (ws_size >= NEED_A) {
    // ---- Tier A: full-batch bf16 path ----
    __hip_bfloat16* xb     = (__hip_bfloat16*)base;              // 32 MiB
    __hip_bfloat16* wqkvb  = (__hip_bfloat16*)(base + 32 * MB);  // 24 MiB
    __hip_bfloat16* wprojb = (__hip_bfloat16*)(base + 56 * MB);  //  8 MiB
    __hip_bfloat16* qk     = (__hip_bfloat16*)(base + 64 * MB);  // 64 MiB

    convert_bf16<<<(BSZ * SEQ * DIM) / 2048, 256, 0, stream>>>(d_in[0], xb, flag);
    convert_bf16<<<(3 * DIM * DIM) / 2048, 256, 0, stream>>>(d_in[1], wqkvb, flag);
    convert_bf16<<<(DIM * DIM) / 2048, 256, 0, stream>>>(d_in[2], wprojb, flag);

    gemm_qkv_full<<<dim3((BSZ * SEQ) / 128, (3 * DIM) / 128), 256, 0, stream>>>(
        xb, wqkvb, qk, d_out, flag);
    norm_rope<<<(BSZ * SEQ * 2 * NH) / 4, 256, 0, stream>>>(qk, qwb, kwb);
    flash_attn<<<dim3(SEQ / 128, NH, BSZ), 512, 0, stream>>>(qk, d_out, flag, 0);
    gemm_proj_full<<<dim3((BSZ * SEQ) / 128, DIM / 128), 256, 0, stream>>>(
        qk, wprojb, d_out, flag);
  } else {
    // ---- Tier B: per-batch fallback ----
    __hip_bfloat16* qk = (__hip_bfloat16*)base;  // 16 MiB, reused per batch
    for (int b = 0; b < BSZ; ++b) {
      gemm_qkv<<<dim3(SEQ / 128, (3 * DIM) / 128), 256, 0, stream>>>(
          d_in[0], d_in[1], qk, d_out, flag, b);
      norm_rope<<<(SEQ * 2 * NH) / 4, 256, 0, stream>>>(qk, qwb, kwb);
      flash_attn<<<dim3(SEQ / 128, NH, 1), 512, 0, stream>>>(qk, d_out, flag, b);
      gemm_proj<<<dim3(SEQ / 128, DIM / 128), 256, 0, stream>>>(
          qk, d_in[2], d_out, flag, b);
    }
  }
}

// Round 8
// 781.872 us; speedup vs baseline: 1.2368x; 1.0152x over previous
//
// ===========================================================================
// FlowerAttention fused pipeline (MI355X / gfx950).
//
// v7 = v6 + flash_attn counted-vmcnt 2-phase pipeline (v2's schedule, proven
// correct in R2, now viable at 16-row tiling: 88 VGPR + ~20 < 128 cliff)
// + T5 s_setprio around MFMA clusters (attn-proven +4-7%).
// Schedule invariant (2 GLDS/thread per stage): steady state 4 outstanding
// {K-next(2 old), V-next(2 new)}; vmcnt(2) at QK^T drains K, vmcnt(2) at PV
// drains V; iter-0 wait also drains the 4 aQ vector loads. Never vmcnt(0)
// until the last tile. Single K/V buffers (32 KB LDS): overwrite-after-
// consume is safe because each wave's MFMAs (which force lgkmcnt drain)
// precede the "consumed" barrier.
// GEMMs untouched this round (m97 structure ~ceiling at 737 TF; 256^2
// 8-phase rewrite is the next, higher-risk lever).
// Predicted: flash ~250 -> ~200-220us, VGPR<=128, total ~745-755us.
// ===========================================================================
#include <hip/hip_runtime.h>
#include <hip/hip_bf16.h>

#define BSZ 4
#define SEQ 2048
#define DIM 2048
#define NH 16
#define HD 128
#define QK_LD 4096  // row stride of packed Q|K workspace
#define SCALE 0.08838834764831845f
// SCALE * log2(e): softmax done in log2 domain (exp2 is the native HW op)
#define SC2 0.12751742910198f

typedef __attribute__((ext_vector_type(8))) short bf16x8;
typedef __attribute__((ext_vector_type(4))) float f32x4;

// Async global->LDS, 16B per lane. LDS dest = wave-uniform base + lane*16.
#define GLDS16(g, l)                                                           \
  __builtin_amdgcn_global_load_lds(                                           \
      (const __attribute__((address_space(1))) void*)(g),                     \
      (__attribute__((address_space(3))) void*)(l), 16, 0, 0)

__device__ inline short f2b(float f) {
  __hip_bfloat16 h = __float2bfloat16(f);
  short s;
  __builtin_memcpy(&s, &h, 2);
  return s;
}

// Load 16 contiguous fp32, convert to bf16, store 32B to LDS (two b128).
__device__ inline void stage16(const float* gp, __hip_bfloat16* lp) {
  float4 q0 = ((const float4*)gp)[0], q1 = ((const float4*)gp)[1];
  float4 q2 = ((const float4*)gp)[2], q3 = ((const float4*)gp)[3];
  bf16x8 v0, v1;
  v0[0] = f2b(q0.x); v0[1] = f2b(q0.y); v0[2] = f2b(q0.z); v0[3] = f2b(q0.w);
  v0[4] = f2b(q1.x); v0[5] = f2b(q1.y); v0[6] = f2b(q1.z); v0[7] = f2b(q1.w);
  v1[0] = f2b(q2.x); v1[1] = f2b(q2.y); v1[2] = f2b(q2.z); v1[3] = f2b(q2.w);
  v1[4] = f2b(q3.x); v1[5] = f2b(q3.y); v1[6] = f2b(q3.z); v1[7] = f2b(q3.w);
  *(bf16x8*)lp = v0;
  *(bf16x8*)(lp + 8) = v1;
}

// Per-batch output slice base, dtype-aware (fl=1: bf16, fl=0: fp32).
__device__ inline char* out_slice(void* outv, int b, int fl) {
  return (char*)outv + (size_t)b * (size_t)SEQ * DIM * (fl ? 2u : 4u);
}

// T1: XCD-aware bijective block remap (requires nwg % 8 == 0).
__device__ inline void xcd_remap(long& bm, long& bn) {
  int nwg = gridDim.x * gridDim.y;
  int lin = blockIdx.y * gridDim.x + blockIdx.x;
  int cpx = nwg >> 3;
  lin = (lin & 7) * cpx + (lin >> 3);
  bm = (long)(lin % gridDim.x) * 128;
  bn = (long)(lin / gridDim.x) * 128;
}

// ---------------------------------------------------------------------------
// Detect input dtype from w_qkv bit patterns; canonicalize qw/kw to bf16.
// ---------------------------------------------------------------------------
__global__ __launch_bounds__(256)
void detect_canon(const unsigned int* __restrict__ wbits,
                  const void* __restrict__ qw, const void* __restrict__ kw,
                  __hip_bfloat16* __restrict__ qwb,
                  __hip_bfloat16* __restrict__ kwb, int* __restrict__ flag) {
  __shared__ int cnt;
  const int t = threadIdx.x;
  if (t == 0) cnt = 0;
  __syncthreads();
  int local = 0;
  for (int i = 0; i < 4; ++i) {
    unsigned int e = (wbits[t * 4 + i] >> 7) & 0xFF;
    if (e >= 96 && e < 160) local++;
  }
  atomicAdd(&cnt, local);
  __syncthreads();
  const int f = (cnt >= 768) ? 1 : 0;  // 1 = bf16 tensors, 0 = fp32 tensors
  if (t == 0) *flag = f;
  if (t < 128)
    qwb[t] = f ? ((const __hip_bfloat16*)qw)[t]
               : __float2bfloat16(((const float*)qw)[t]);
  else
    kwb[t - 128] = f ? ((const __hip_bfloat16*)kw)[t - 128]
                     : __float2bfloat16(((const float*)kw)[t - 128]);
}

// ---------------------------------------------------------------------------
// Elementwise canonicalize a tensor to bf16 (8 elts/thread). fl=1: raw copy.
// ---------------------------------------------------------------------------
__global__ __launch_bounds__(256)
void convert_bf16(const void* __restrict__ in, __hip_bfloat16* __restrict__ out,
                  const int* __restrict__ flag) {
  const int fl = *flag;
  long i = ((long)blockIdx.x * 256 + threadIdx.x) * 8;
  if (fl) {
    *(float4*)(out + i) = *(const float4*)((const __hip_bfloat16*)in + i);
  } else {
    const float* p = (const float*)in + i;
    float4 a = ((const float4*)p)[0], b = ((const float4*)p)[1];
    bf16x8 o;
    o[0] = f2b(a.x); o[1] = f2b(a.y); o[2] = f2b(a.z); o[3] = f2b(a.w);
    o[4] = f2b(b.x); o[5] = f2b(b.y); o[6] = f2b(b.z); o[7] = f2b(b.w);
    *(bf16x8*)(out + i) = o;
  }
}

// ===========================================================================
// TIER A GEMMs (m97 structure, both operands via global_load_lds).
// ===========================================================================

__global__ __launch_bounds__(256)
void gemm_qkv_full(const __hip_bfloat16* __restrict__ A,
                   const __hip_bfloat16* __restrict__ B,
                   __hip_bfloat16* __restrict__ qk, void* __restrict__ outv,
                   const int* __restrict__ flag) {
  __shared__ __hip_bfloat16 As[128 * 32];
  __shared__ __hip_bfloat16 Bs[128 * 32];
  const int t = threadIdx.x, wave = t >> 6, lane = t & 63;
  const int quad = lane >> 4, l16 = lane & 15;
  const int wm = (wave & 1) * 64, wn = (wave >> 1) * 64;
  long bm, bn;
  xcd_remap(bm, bn);
  const int fl = *flag;

  f32x4 acc[4][4] = {};
  for (int k0 = 0; k0 < DIM; k0 += 32) {
    __syncthreads();
    for (int i = 0; i < 2; ++i) {
      int c = wave * 64 + lane + i * 256;
      int row = c >> 2, kc = c & 3;
      GLDS16(A + (bm + row) * DIM + k0 + kc * 8, As + (wave * 64 + i * 256) * 8);
      GLDS16(B + (bn + row) * DIM + k0 + kc * 8, Bs + (wave * 64 + i * 256) * 8);
    }
    __syncthreads();
    bf16x8 aF[4], bF[4];
    for (int mt = 0; mt < 4; ++mt)
      aF[mt] = *(const bf16x8*)(As + (wm + mt * 16 + l16) * 32 + quad * 8);
    for (int nt = 0; nt < 4; ++nt)
      bF[nt] = *(const bf16x8*)(Bs + (wn + nt * 16 + l16) * 32 + quad * 8);
    for (int mt = 0; mt < 4; ++mt)
      for (int nt = 0; nt < 4; ++nt)
        acc[mt][nt] = __builtin_amdgcn_mfma_f32_16x16x32_bf16(
            aF[mt], bF[nt], acc[mt][nt], 0, 0, 0);
  }

  if (bn < 4096) {  // Q|K block
    for (int mt = 0; mt < 4; ++mt) {
      long gr = bm + wm + mt * 16 + quad * 4;
      for (int nt = 0; nt < 4; ++nt) {
        long gc = bn + wn + nt * 16 + l16;
        for (int r = 0; r < 4; ++r)
          qk[(gr + r) * QK_LD + gc] = __float2bfloat16(acc[mt][nt][r]);
      }
    }
  } else {  // V block: transposed bf16 store into the owning batch's slice
    for (int mt = 0; mt < 4; ++mt) {
      long gr = bm + wm + mt * 16 + quad * 4;
      __hip_bfloat16* vtb = (__hip_bfloat16*)out_slice(outv, (int)(gr >> 11), fl);
      long s = gr & 2047;
      for (int nt = 0; nt < 4; ++nt) {
        long col = bn - 4096 + wn + nt * 16 + l16;  // h*128 + d
        for (int r = 0; r < 4; ++r)
          vtb[col * SEQ + s + r] = __float2bfloat16(acc[mt][nt][r]);
      }
    }
  }
}

__global__ __launch_bounds__(256)
void gemm_proj_full(const __hip_bfloat16* __restrict__ A,
                    const __hip_bfloat16* __restrict__ B,
                    void* __restrict__ outv, const int* __restrict__ flag) {
  __shared__ __hip_bfloat16 As[128 * 32];
  __shared__ __hip_bfloat16 Bs[128 * 32];
  const int t = threadIdx.x, wave = t >> 6, lane = t & 63;
  const int quad = lane >> 4, l16 = lane & 15;
  const int wm = (wave & 1) * 64, wn = (wave >> 1) * 64;
  long bm, bn;
  xcd_remap(bm, bn);
  const int fl = *flag;

  f32x4 acc[4][4] = {};
  for (int k0 = 0; k0 < DIM; k0 += 32) {
    __syncthreads();
    for (int i = 0; i < 2; ++i) {
      int c = wave * 64 + lane + i * 256;
      int row = c >> 2, kc = c & 3;
      GLDS16(A + (bm + row) * QK_LD + k0 + kc * 8, As + (wave * 64 + i * 256) * 8);
      GLDS16(B + (bn + row) * DIM + k0 + kc * 8, Bs + (wave * 64 + i * 256) * 8);
    }
    __syncthreads();
    bf16x8 aF[4], bF[4];
    for (int mt = 0; mt < 4; ++mt)
      aF[mt] = *(const bf16x8*)(As + (wm + mt * 16 + l16) * 32 + quad * 8);
    for (int nt = 0; nt < 4; ++nt)
      bF[nt] = *(const bf16x8*)(Bs + (wn + nt * 16 + l16) * 32 + quad * 8);
    for (int mt = 0; mt < 4; ++mt)
      for (int nt = 0; nt < 4; ++nt)
        acc[mt][nt] = __builtin_amdgcn_mfma_f32_16x16x32_bf16(
            aF[mt], bF[nt], acc[mt][nt], 0, 0, 0);
  }

  for (int mt = 0; mt < 4; ++mt) {
    long gr = bm + wm + mt * 16 + quad * 4;
    for (int nt = 0; nt < 4; ++nt) {
      long gc = bn + wn + nt * 16 + l16;
      for (int r = 0; r < 4; ++r) {
        long idx = (gr + r) * DIM + gc;
        if (fl) ((__hip_bfloat16*)outv)[idx] = __float2bfloat16(acc[mt][nt][r]);
        else    ((float*)outv)[idx] = acc[mt][nt][r];
      }
    }
  }
}

// ===========================================================================
// TIER B GEMMs (per-batch, dual staging — fallback, known-good).
// ===========================================================================

__global__ __launch_bounds__(256)
void gemm_qkv(const void* __restrict__ xin, const void* __restrict__ win,
              __hip_bfloat16* __restrict__ qk, void* __restrict__ outv,
              const int* __restrict__ flag, int b) {
  __shared__ __hip_bfloat16 As[128 * 32];
  __shared__ __hip_bfloat16 Bs[128 * 32];
  const int t = threadIdx.x, wave = t >> 6, lane = t & 63;
  const int quad = lane >> 4, l16 = lane & 15;
  const int wm = (wave & 1) * 64, wn = (wave >> 1) * 64;
  const long bm = (long)blockIdx.x * 128, bn = (long)blockIdx.y * 128;
  const int fl = *flag;
  const __hip_bfloat16* Ab = (const __hip_bfloat16*)xin + (long)b * SEQ * DIM;
  const __hip_bfloat16* Bb = (const __hip_bfloat16*)win;
  const float* Af = (const float*)xin + (long)b * SEQ * DIM;
  const float* Bf = (const float*)win;

  f32x4 acc[4][4] = {};
  for (int k0 = 0; k0 < DIM; k0 += 32) {
    __syncthreads();
    if (fl) {
      for (int i = 0; i < 2; ++i) {
        int c = wave * 64 + lane + i * 256;
        int row = c >> 2, kc = c & 3;
        GLDS16(Ab + (bm + row) * DIM + k0 + kc * 8, As + (wave * 64 + i * 256) * 8);
        GLDS16(Bb + (bn + row) * DIM + k0 + kc * 8, Bs + (wave * 64 + i * 256) * 8);
      }
    } else {
      int row = t >> 1, cb = k0 + (t & 1) * 16;
      stage16(Af + (bm + row) * DIM + cb, As + t * 16);
      stage16(Bf + (bn + row) * DIM + cb, Bs + t * 16);
    }
    __syncthreads();
    bf16x8 aF[4], bF[4];
    for (int mt = 0; mt < 4; ++mt)
      aF[mt] = *(const bf16x8*)(As + (wm + mt * 16 + l16) * 32 + quad * 8);
    for (int nt = 0; nt < 4; ++nt)
      bF[nt] = *(const bf16x8*)(Bs + (wn + nt * 16 + l16) * 32 + quad * 8);
    for (int mt = 0; mt < 4; ++mt)
      for (int nt = 0; nt < 4; ++nt)
        acc[mt][nt] = __builtin_amdgcn_mfma_f32_16x16x32_bf16(
            aF[mt], bF[nt], acc[mt][nt], 0, 0, 0);
  }

  if (bn < 4096) {
    for (int mt = 0; mt < 4; ++mt) {
      long gr = bm + wm + mt * 16 + quad * 4;
      for (int nt = 0; nt < 4; ++nt) {
        long gc = bn + wn + nt * 16 + l16;
        for (int r = 0; r < 4; ++r)
          qk[(gr + r) * QK_LD + gc] = __float2bfloat16(acc[mt][nt][r]);
      }
    }
  } else {
    __hip_bfloat16* vtb = (__hip_bfloat16*)out_slice(outv, b, fl);
    for (int mt = 0; mt < 4; ++mt) {
      long gr = bm + wm + mt * 16 + quad * 4;
      for (int nt = 0; nt < 4; ++nt) {
        long col = bn - 4096 + wn + nt * 16 + l16;
        for (int r = 0; r < 4; ++r)
          vtb[col * SEQ + gr + r] = __float2bfloat16(acc[mt][nt][r]);
      }
    }
  }
}

__global__ __launch_bounds__(256)
void gemm_proj(const __hip_bfloat16* __restrict__ A, const void* __restrict__ win,
               void* __restrict__ outv, const int* __restrict__ flag, int b) {
  __shared__ __hip_bfloat16 As[128 * 32];
  __shared__ __hip_bfloat16 Bs[128 * 32];
  const int t = threadIdx.x, wave = t >> 6, lane = t & 63;
  const int quad = lane >> 4, l16 = lane & 15;
  const int wm = (wave & 1) * 64, wn = (wave >> 1) * 64;
  const long bm = (long)blockIdx.x * 128, bn = (long)blockIdx.y * 128;
  const int fl = *flag;
  const __hip_bfloat16* Bb = (const __hip_bfloat16*)win;
  const float* Bf = (const float*)win;

  f32x4 acc[4][4] = {};
  for (int k0 = 0; k0 < DIM; k0 += 32) {
    __syncthreads();
    for (int i = 0; i < 2; ++i) {
      int c = wave * 64 + lane + i * 256;
      int row = c >> 2, kc = c & 3;
      GLDS16(A + (bm + row) * QK_LD + k0 + kc * 8, As + (wave * 64 + i * 256) * 8);
    }
    if (fl) {
      for (int i = 0; i < 2; ++i) {
        int c = wave * 64 + lane + i * 256;
        int row = c >> 2, kc = c & 3;
        GLDS16(Bb + (bn + row) * DIM + k0 + kc * 8, Bs + (wave * 64 + i * 256) * 8);
      }
    } else {
      int row = t >> 1, cb = k0 + (t & 1) * 16;
      stage16(Bf + (bn + row) * DIM + cb, Bs + t * 16);
    }
    __syncthreads();
    bf16x8 aF[4], bF[4];
    for (int mt = 0; mt < 4; ++mt)
      aF[mt] = *(const bf16x8*)(As + (wm + mt * 16 + l16) * 32 + quad * 8);
    for (int nt = 0; nt < 4; ++nt)
      bF[nt] = *(const bf16x8*)(Bs + (wn + nt * 16 + l16) * 32 + quad * 8);
    for (int mt = 0; mt < 4; ++mt)
      for (int nt = 0; nt < 4; ++nt)
        acc[mt][nt] = __builtin_amdgcn_mfma_f32_16x16x32_bf16(
            aF[mt], bF[nt], acc[mt][nt], 0, 0, 0);
  }

  char* Cb = out_slice(outv, b, fl);
  for (int mt = 0; mt < 4; ++mt) {
    long gr = bm + wm + mt * 16 + quad * 4;
    for (int nt = 0; nt < 4; ++nt) {
      long gc = bn + wn + nt * 16 + l16;
      for (int r = 0; r < 4; ++r) {
        long idx = (gr + r) * DIM + gc;
        if (fl) ((__hip_bfloat16*)Cb)[idx] = __float2bfloat16(acc[mt][nt][r]);
        else    ((float*)Cb)[idx] = acc[mt][nt][r];
      }
    }
  }
}

// ===========================================================================
// Shared kernels.
// ===========================================================================

// Per-row RMSNorm + RoPE, vectorized: lane loads uint (2 bf16), shfl
// redistributes to the (d, d+64) RoPE pairing, inverse shfl scatters back.
__global__ __launch_bounds__(256)
void norm_rope(__hip_bfloat16* __restrict__ qk,
               const __hip_bfloat16* __restrict__ qwb,
               const __hip_bfloat16* __restrict__ kwb) {
  const int wave = threadIdx.x >> 6, lane = threadIdx.x & 63;
  const int gid = blockIdx.x * 4 + wave;
  const int h = gid & 15, tt = (gid >> 4) & 1, row = gid >> 5;
  const int s = row & 2047;

  __hip_bfloat16* p = qk + (long)row * QK_LD + tt * DIM + h * HD;
  unsigned int u = ((const unsigned int*)p)[lane];  // elems (2l, 2l+1)

  // gather pair (d=lane, d=lane+64)
  unsigned int x = (unsigned int)__shfl((int)u, lane >> 1);
  unsigned int y = (unsigned int)__shfl((int)u, 32 + (lane >> 1));
  float v1 = __uint_as_float((lane & 1) ? (x & 0xFFFF0000u) : (x << 16));
  float v2 = __uint_as_float((lane & 1) ? (y & 0xFFFF0000u) : (y << 16));

  float ss = v1 * v1 + v2 * v2;
  for (int off = 1; off < 64; off <<= 1) ss += __shfl_xor(ss, off);
  float inv = rsqrtf(ss * (1.0f / 128.0f) + 1e-6f);

  const __hip_bfloat16* w = tt ? kwb : qwb;
  float n1 = v1 * inv * __bfloat162float(w[lane]);
  float n2 = v2 * inv * __bfloat162float(w[lane + 64]);

  float freq = exp2f(-5.0f * (float)lane * (1.0f / 64.0f));
  float ang = (float)s * freq;
  float c = cosf(ang), sn = sinf(ang);
  float r1 = n1 * c - n2 * sn;  // elem d = lane
  float r2 = n2 * c + n1 * sn;  // elem d = lane + 64

  // scatter back: lane stores elems (2l, 2l+1)
  float z1lo = __shfl(r1, (2 * lane) & 63), z2lo = __shfl(r2, (2 * lane) & 63);
  float z1hi = __shfl(r1, (2 * lane + 1) & 63), z2hi = __shfl(r2, (2 * lane + 1) & 63);
  float lo = (lane < 32) ? z1lo : z2lo;
  float hi = (lane < 32) ? z1hi : z2hi;
  unsigned int ou = (unsigned int)(unsigned short)f2b(lo) |
                    ((unsigned int)(unsigned short)f2b(hi) << 16);
  ((unsigned int*)p)[lane] = ou;
}

// ---------------------------------------------------------------------------
// Flash attention, non-causal. Block = 128-query tile for one (b,h);
// 8 waves x 16 query rows (512 threads). K-tiles of 64. Swapped QK^T
// (v6, in-register P). v7 adds the counted-vmcnt 2-phase pipeline (v2's
// proven schedule): stage K(t+1) after the Ks-consumed barrier (hides under
// softmax+PV), stage V(t+1) after the Vs-consumed barrier (hides under the
// next QK^T). 2 GLDS/thread per stage -> vmcnt(2) counted waits; vmcnt(0)
// only on the last tile. LDS = Ks 16K + Vs 16K = 32 KB. T5 setprio around
// both MFMA clusters.
// ---------------------------------------------------------------------------
#define FA_STAGE_K(J)                                                          \
  _Pragma("unroll")                                                            \
  for (int i_ = 0; i_ < 2; ++i_) {                                             \
    int f_ = t + i_ * 512;                                                     \
    int kk_ = f_ & 3, row_ = (f_ >> 2) & 63, ks_ = f_ >> 8;                    \
    GLDS16(Kg + (long)((J) + row_) * QK_LD + ks_ * 32 +                        \
               (kk_ ^ ((row_ >> 1) & 3)) * 8,                                  \
           Ks + (t + i_ * 512) * 8);                                           \
  }
#define FA_STAGE_V(J)                                                          \
  _Pragma("unroll")                                                            \
  for (int i_ = 0; i_ < 2; ++i_) {                                             \
    int f_ = t + i_ * 512;                                                     \
    int kk_ = f_ & 3, dim_ = (f_ >> 2) & 127, ks2_ = f_ >> 9;                  \
    GLDS16(Vt + (long)dim_ * SEQ + (J) + ks2_ * 32 +                           \
               (kk_ ^ ((dim_ >> 1) & 3)) * 8,                                  \
           Vs + (t + i_ * 512) * 8);                                           \
  }
#define FA_WAIT2 asm volatile("s_waitcnt vmcnt(2)" ::: "memory")
#define FA_WAIT0 asm volatile("s_waitcnt vmcnt(0)" ::: "memory")
#define FA_BAR                                                                 \
  do {                                                                         \
    asm volatile("" ::: "memory");                                             \
    __builtin_amdgcn_s_barrier();                                              \
    asm volatile("" ::: "memory");                                             \
  } while (0)

__global__ __launch_bounds__(512)
void flash_attn(__hip_bfloat16* __restrict__ qkbase, void* __restrict__ outv,
                const int* __restrict__ flag, int b0) {
  __shared__ __hip_bfloat16 Ks[4 * 64 * 32];
  __shared__ __hip_bfloat16 Vs[2 * 128 * 32];

  const int t = threadIdx.x, wave = t >> 6, lane = t & 63;
  const int quad = lane >> 4, l16 = lane & 15;
  // swizzled 8-elem slot for all fragment reads (row bits 1:2 come from l16)
  const int swz = (quad ^ ((l16 >> 1) & 3)) * 8;
  const int q0 = blockIdx.x * 128, h = blockIdx.y;
  const int b = b0 + blockIdx.z;
  const int fl = *flag;
  __hip_bfloat16* qk = qkbase + (long)blockIdx.z * SEQ * QK_LD;
  __hip_bfloat16* Qg = qk + h * HD;
  const __hip_bfloat16* Kg = Qg + DIM;
  const __hip_bfloat16* Vt =
      (const __hip_bfloat16*)out_slice(outv, b, fl) + (long)h * HD * SEQ;

  // exchange source lanes (same l16, quad-pair determined by own quad&1)
  const int srcA = ((lane >> 4) & 1) * 32 + l16;  // quad (quad&1)*2
  const int srcB = srcA + 16;                     // quad (quad&1)*2 + 1
  const bool hiq = (quad >= 2);

  // Q fragments in registers: rows q0 + wave*16 + l16
  bf16x8 aQ[4];
#pragma unroll
  for (int ks = 0; ks < 4; ++ks)
    aQ[ks] = *(const bf16x8*)(Qg +
        (long)(q0 + wave * 16 + l16) * QK_LD + ks * 32 + quad * 8);

  f32x4 oacc[8] = {};
  float m_run = -1e30f, l_run = 0.0f;  // per-lane: query l16, own 16 keys

  // prologue: issue K(0), V(0). Outstanding: aQ(4) + K(2) + V(2).
  FA_STAGE_K(0);
  FA_STAGE_V(0);

  for (int j0 = 0; j0 < SEQ; j0 += 64) {
    const bool more = (j0 + 64 < SEQ);

    // K(cur) staged (also drains aQ on iter 0); V(cur) stays in flight.
    FA_WAIT2;
    FA_BAR;

    // S^T = K Q^T: sacc[nt][r] = S[key nt*16+quad*4+r][query l16]
    f32x4 sacc[4] = {};
    __builtin_amdgcn_s_setprio(1);
#pragma unroll
    for (int ks = 0; ks < 4; ++ks)
#pragma unroll
      for (int nt = 0; nt < 4; ++nt) {
        bf16x8 bK = *(const bf16x8*)(Ks + (ks * 64 + nt * 16 + l16) * 32 + swz);
        sacc[nt] = __builtin_amdgcn_mfma_f32_16x16x32_bf16(
            bK, aQ[ks], sacc[nt], 0, 0, 0);
      }
    __builtin_amdgcn_s_setprio(0);

    FA_BAR;  // Ks consumed by all waves (MFMA use forced lgkm drain)
    if (more) { FA_STAGE_K(j0 + 64); }  // hides under softmax + PV

    // lane-local softmax (query l16, 16 keys per lane)
    float p[16];
#pragma unroll
    for (int nt = 0; nt < 4; ++nt)
#pragma unroll
      for (int r = 0; r < 4; ++r) p[nt * 4 + r] = sacc[nt][r] * SC2;
    float mx = p[0];
#pragma unroll
    for (int i = 1; i < 16; ++i) mx = fmaxf(mx, p[i]);
    mx = fmaxf(mx, __shfl_xor(mx, 16));
    mx = fmaxf(mx, __shfl_xor(mx, 32));
    // defer-max (T13): rescale only when some query's max grew past THR=8
    if (__any(mx > m_run + 8.0f)) {
      float mnew = fmaxf(m_run, mx);
      float alpha = exp2f(m_run - mnew);
      m_run = mnew;
      l_run *= alpha;
      // oacc rows are queries quad*4+r: fetch that query's alpha
#pragma unroll
      for (int r = 0; r < 4; ++r) {
        float ar = __shfl(alpha, quad * 20 + r);
#pragma unroll
        for (int n = 0; n < 8; ++n) oacc[n][r] *= ar;
      }
    }
    // P = exp2(p - m); pack to bf16 pairs W[nt][h] (keys ascending)
    unsigned int W[4][2];
    float sum = 0.0f;
#pragma unroll
    for (int nt = 0; nt < 4; ++nt) {
      float e0 = exp2f(p[nt * 4 + 0] - m_run), e1 = exp2f(p[nt * 4 + 1] - m_run);
      float e2 = exp2f(p[nt * 4 + 2] - m_run), e3 = exp2f(p[nt * 4 + 3] - m_run);
      sum += (e0 + e1) + (e2 + e3);
      W[nt][0] = (unsigned int)(unsigned short)f2b(e0) |
                 ((unsigned int)(unsigned short)f2b(e1) << 16);
      W[nt][1] = (unsigned int)(unsigned short)f2b(e2) |
                 ((unsigned int)(unsigned short)f2b(e3) << 16);
    }
    l_run += sum;

    // exchange: aP[ks2] word w = W[2ks2+(quad>>1)][w&1] from lane
    // ((quad&1)*2 + (w>>1))*16 + l16
    union { unsigned int u[4]; bf16x8 v; } ap[2];
#pragma unroll
    for (int ks2 = 0; ks2 < 2; ++ks2) {
#pragma unroll
      for (int hh = 0; hh < 2; ++hh) {
        unsigned int lo0 = (unsigned int)__shfl((int)W[2 * ks2][hh], srcA);
        unsigned int hi0 = (unsigned int)__shfl((int)W[2 * ks2 + 1][hh], srcA);
        unsigned int lo1 = (unsigned int)__shfl((int)W[2 * ks2][hh], srcB);
        unsigned int hi1 = (unsigned int)__shfl((int)W[2 * ks2 + 1][hh], srcB);
        ap[ks2].u[hh] = hiq ? hi0 : lo0;
        ap[ks2].u[2 + hh] = hiq ? hi1 : lo1;
      }
    }

    // V(cur) staged (keep K-next in flight); on last tile drain all.
    if (more) { FA_WAIT2; } else { FA_WAIT0; }
    FA_BAR;

    // O += P @ V: A = aP (rows=queries), B = V (rows=dims)
    __builtin_amdgcn_s_setprio(1);
#pragma unroll
    for (int ks2 = 0; ks2 < 2; ++ks2) {
      bf16x8 aP = ap[ks2].v;
#pragma unroll
      for (int n = 0; n < 8; ++n) {
        bf16x8 bV = *(const bf16x8*)(Vs + (ks2 * 128 + n * 16 + l16) * 32 + swz);
        oacc[n] = __builtin_amdgcn_mfma_f32_16x16x32_bf16(
            aP, bV, oacc[n], 0, 0, 0);
      }
    }
    __builtin_amdgcn_s_setprio(0);

    FA_BAR;  // Vs consumed by all waves
    if (more) { FA_STAGE_V(j0 + 64); }  // hides under next QK^T
  }

  // epilogue: total l per query (reduce over the 4 quads), write O
  float l = l_run;
  l += __shfl_xor(l, 16);
  l += __shfl_xor(l, 32);
  float rl = 1.0f / l;  // for query l16
#pragma unroll
  for (int r = 0; r < 4; ++r) {
    float rlr = __shfl(rl, quad * 20 + r);  // for query quad*4+r
    long s = q0 + wave * 16 + quad * 4 + r;
    for (int n = 0; n < 8; ++n)
      qk[s * QK_LD + h * HD + n * 16 + l16] =
          __float2bfloat16(oacc[n][r] * rlr);
  }
}

// ---------------------------------------------------------------------------
extern "C" void kernel_launch(void* const* d_in, const int* in_sizes, int n_in,
                              void* d_out, int out_size, void* d_ws, size_t ws_size,
                              hipStream_t stream) {
  int* flag = (int*)d_ws;
  __hip_bfloat16* qwb = (__hip_bfloat16*)((char*)d_ws + 64);
  __hip_bfloat16* kwb = qwb + 128;
  char* base = (char*)d_ws + 1024;

  detect_canon<<<1, 256, 0, stream>>>((const unsigned int*)d_in[1], d_in[3],
                                      d_in[4], qwb, kwb, flag);

  const size_t MB = 1024ull * 1024ull;
  const size_t NEED_A = 1024 + 128 * MB;

  if (ws_size >= NEED_A) {
    // ---- Tier A: full-batch bf16 path ----
    __hip_bfloat16* xb     = (__hip_bfloat16*)base;              // 32 MiB
    __hip_bfloat16* wqkvb  = (__hip_bfloat16*)(base + 32 * MB);  // 24 MiB
    __hip_bfloat16* wprojb = (__hip_bfloat16*)(base + 56 * MB);  //  8 MiB
    __hip_bfloat16* qk     = (__hip_bfloat16*)(base + 64 * MB);  // 64 MiB

    convert_bf16<<<(BSZ * SEQ * DIM) / 2048, 256, 0, stream>>>(d_in[0], xb, flag);
    convert_bf16<<<(3 * DIM * DIM) / 2048, 256, 0, stream>>>(d_in[1], wqkvb, flag);
    convert_bf16<<<(DIM * DIM) / 2048, 256, 0, stream>>>(d_in[2], wprojb, flag);

    gemm_qkv_full<<<dim3((BSZ * SEQ) / 128, (3 * DIM) / 128), 256, 0, stream>>>(
        xb, wqkvb, qk, d_out, flag);
    norm_rope<<<(BSZ * SEQ * 2 * NH) / 4, 256, 0, stream>>>(qk, qwb, kwb);
    flash_attn<<<dim3(SEQ / 128, NH, BSZ), 512, 0, stream>>>(qk, d_out, flag, 0);
    gemm_proj_full<<<dim3((BSZ * SEQ) / 128, DIM / 128), 256, 0, stream>>>(
        qk, wprojb, d_out, flag);
  } else {
    // ---- Tier B: per-batch fallback ----
    __hip_bfloat16* qk = (__hip_bfloat16*)base;  // 16 MiB, reused per batch
    for (int b = 0; b < BSZ; ++b) {
      gemm_qkv<<<dim3(SEQ / 128, (3 * DIM) / 128), 256, 0, stream>>>(
          d_in[0], d_in[1], qk, d_out, flag, b);
      norm_rope<<<(SEQ * 2 * NH) / 4, 256, 0, stream>>>(qk, qwb, kwb);
      flash_attn<<<dim3(SEQ / 128, NH, 1), 512, 0, stream>>>(qk, d_out, flag, b);
      gemm_proj<<<dim3(SEQ / 128, DIM / 128), 256, 0, stream>>>(
          qk, d_in[2], d_out, flag, b);
    }
  }
}